// Round 2
// baseline (1025.718 us; speedup 1.0000x reference)
//
#include <hip/hip_runtime.h>

// CffmTransformerBlock3d3 — fp32, round 2.
// Change vs r0: GEMM upgraded 64x64/4x4 -> 128x128 tile / 8x8 microtile
// (arithmetic-intensity fix: 64 FMA per 64B LDS per thread, was 16 per 32B,
// which was LDS-BW-bound at ~50% VALU util). Attention unchanged.
//
// Pipeline:
//   1. qkv   = x @ qkv_w + qkv_b                      (25088 x 768)
//   2. kvN   = clipN @ qkv_w[:,256:768] + qkv_b[256:] (k,v only; 512 cols)
//   3. attn  : per (window, head): 49 queries x 377 keys flash attention
//              K/V segments: [own window(49) | 4 rolled shifts(196) |
//                             pool0 raw reshape(49) | clip1(49) | clip2(25) | clip3(9)]
//   4. out   = attn @ proj_w + proj_b

#define K_DIM 256

// ---------------- GEMM: C[M,N] = A[M,256] @ W[256,N] + bias ----------------
// 128x128 block tile, 256 threads, 8x8 per-thread microtile, K chunks of 16.
// M must be /128, N must be /128.
__global__ __launch_bounds__(256)
void gemm_bias_kernel(const float* __restrict__ A,
                      const float* __restrict__ W, int ldw,
                      const float* __restrict__ bias,
                      float* __restrict__ C, int ldc)
{
    __shared__ float As[16][132];   // As[k][m], pad to 132 floats
    __shared__ float Ws[16][132];   // Ws[k][n]

    const int tid = threadIdx.x;
    const int n0 = blockIdx.x * 128;
    const int m0 = blockIdx.y * 128;

    // A staging: thread -> (row am, k-octet ak): 128 rows x 16 k, 8 floats/thread
    const int am = tid >> 1;            // 0..127
    const int ak = (tid & 1) << 3;      // 0 or 8
    // W staging: thread -> (k row wk, col-octet wn): 16 k x 128 n
    const int wk = tid >> 4;            // 0..15
    const int wn = (tid & 15) << 3;     // 0..120

    // compute mapping: 16x16 threads, each owns 8x8 at (tm*8, tn*8)
    const int tm = tid >> 4;            // 0..15
    const int tn = tid & 15;            // 0..15

    float acc[8][8];
#pragma unroll
    for (int i = 0; i < 8; ++i)
#pragma unroll
        for (int j = 0; j < 8; ++j) acc[i][j] = 0.f;

    const float* Arow = A + (size_t)(m0 + am) * K_DIM + ak;
    const float* Wrow = W + (size_t)wk * ldw + n0 + wn;

    for (int k0 = 0; k0 < K_DIM; k0 += 16) {
        const float4 av0 = *(const float4*)(Arow + k0);
        const float4 av1 = *(const float4*)(Arow + k0 + 4);
        const float4 wv0 = *(const float4*)(Wrow + (size_t)k0 * ldw);
        const float4 wv1 = *(const float4*)(Wrow + (size_t)k0 * ldw + 4);
        __syncthreads();   // previous iter compute done before overwrite
        As[ak + 0][am] = av0.x;
        As[ak + 1][am] = av0.y;
        As[ak + 2][am] = av0.z;
        As[ak + 3][am] = av0.w;
        As[ak + 4][am] = av1.x;
        As[ak + 5][am] = av1.y;
        As[ak + 6][am] = av1.z;
        As[ak + 7][am] = av1.w;
        *(float4*)&Ws[wk][wn]     = wv0;
        *(float4*)&Ws[wk][wn + 4] = wv1;
        __syncthreads();
#pragma unroll
        for (int k = 0; k < 16; ++k) {
            float a[8], w[8];
            *(float4*)&a[0] = *(const float4*)&As[k][tm << 3];
            *(float4*)&a[4] = *(const float4*)&As[k][(tm << 3) + 4];
            *(float4*)&w[0] = *(const float4*)&Ws[k][tn << 3];
            *(float4*)&w[4] = *(const float4*)&Ws[k][(tn << 3) + 4];
#pragma unroll
            for (int i = 0; i < 8; ++i)
#pragma unroll
                for (int j = 0; j < 8; ++j)
                    acc[i][j] = fmaf(a[i], w[j], acc[i][j]);
        }
    }

    float b[8];
    *(float4*)&b[0] = *(const float4*)(bias + n0 + (tn << 3));
    *(float4*)&b[4] = *(const float4*)(bias + n0 + (tn << 3) + 4);
#pragma unroll
    for (int i = 0; i < 8; ++i) {
        float* crow = C + (size_t)(m0 + (tm << 3) + i) * ldc + n0 + (tn << 3);
        float4 o0, o1;
        o0.x = acc[i][0] + b[0];
        o0.y = acc[i][1] + b[1];
        o0.z = acc[i][2] + b[2];
        o0.w = acc[i][3] + b[3];
        o1.x = acc[i][4] + b[4];
        o1.y = acc[i][5] + b[5];
        o1.z = acc[i][6] + b[6];
        o1.w = acc[i][7] + b[7];
        *(float4*)crow       = o0;
        *(float4*)(crow + 4) = o1;
    }
}

// ---------------- Attention ----------------
// One wave (64 threads) per (window, head). Lane q<49 owns one query row.
// K/V tiles of 32 keys staged in LDS: lanes 0..31 gather K rows, 32..63 V rows.
// Online softmax, per-tile rescale.
#define NKEYS 377

__global__ __launch_bounds__(64)
void attn_kernel(const float* __restrict__ qkv,    // [25088, 768] q|k|v
                 const float* __restrict__ pool0,  // [512 * 12544]
                 const float* __restrict__ kv1,    // [25088, 512] k|v
                 const float* __restrict__ kv2,    // [12800, 512]
                 const float* __restrict__ kv3,    // [4608, 512]
                 float* __restrict__ out)          // [25088, 256]
{
    __shared__ float Ks[32][36];   // 36-stride: 144B rows, 16B-aligned, spreads banks
    __shared__ float Vs[32][36];

    const int wh = blockIdx.x;         // 0..4095
    const int w  = wh >> 3;            // window 0..511
    const int h  = wh & 7;             // head
    const int b  = w >> 8;             // batch
    const int wi = (w >> 4) & 15;
    const int wj = w & 15;
    const int lane = threadIdx.x;

    float q[32];
    if (lane < 49) {
        const int a = lane / 7, c = lane % 7;
        const int row = (b * 112 + wi * 7 + a) * 112 + wj * 7 + c;
        const float scale = 0.17677669529663687f;   // 32^-0.5
        const float4* qp = (const float4*)(qkv + (size_t)row * 768 + h * 32);
#pragma unroll
        for (int d4 = 0; d4 < 8; ++d4) {
            const float4 v = qp[d4];
            q[d4 * 4 + 0] = v.x * scale;
            q[d4 * 4 + 1] = v.y * scale;
            q[d4 * 4 + 2] = v.z * scale;
            q[d4 * 4 + 3] = v.w * scale;
        }
    }

    float m = -1e30f, l = 0.f;
    float acc[32];
#pragma unroll
    for (int d = 0; d < 32; ++d) acc[d] = 0.f;

    const int  j   = lane & 31;
    const bool isV = lane >= 32;

    for (int tile = 0; tile < 12; ++tile) {
        const int t0 = tile * 32;
        const int nk = (NKEYS - t0 < 32) ? (NKEYS - t0) : 32;

        // ---- gather K/V rows into LDS ----
        {
            float4* dst = (float4*)(isV ? Vs[j] : Ks[j]);
            if (j < nk) {
                const int t = t0 + j;
                const float* kp;
                const float* vp;
                if (t < 245) {
                    int a, c, hh, ww;
                    if (t < 49) {
                        a = t / 7; c = t % 7;
                        hh = wi * 7 + a; ww = wj * 7 + c;
                    } else {
                        const int u  = t - 49;
                        const int si = u / 49;
                        const int r  = u % 49;
                        a = r / 7; c = r % 7;
                        const int sh = (si < 2) ? -3 : 3;      // shifts: (-3,-3)(-3,3)(3,-3)(3,3)
                        const int sw = (si & 1) ? 3 : -3;
                        hh = (wi * 7 + a - sh + 112) % 112;    // roll: out[i] = in[(i - s) mod n]
                        ww = (wj * 7 + c - sw + 112) % 112;
                    }
                    const int row = (b * 112 + hh) * 112 + ww;
                    kp = qkv + (size_t)row * 768 + 256 + h * 32;
                    vp = qkv + (size_t)row * 768 + 512 + h * 32;
                } else if (t < 294) {
                    // pool0: raw reshape (512, 8, 49, 32) of (512, 7*7*256)
                    const int tp = t - 245;
                    const float* p = pool0 + (size_t)w * 12544 + h * 1568 + tp * 32;
                    kp = p; vp = p;
                } else if (t < 343) {
                    const int tc = t - 294;
                    const float* p = kv1 + (size_t)(w * 49 + tc) * 512 + h * 32;
                    kp = p; vp = p + 256;
                } else if (t < 368) {
                    const int tc = t - 343;
                    const float* p = kv2 + (size_t)(w * 25 + tc) * 512 + h * 32;
                    kp = p; vp = p + 256;
                } else {
                    const int tc = t - 368;
                    const float* p = kv3 + (size_t)(w * 9 + tc) * 512 + h * 32;
                    kp = p; vp = p + 256;
                }
                const float4* src = (const float4*)(isV ? vp : kp);
#pragma unroll
                for (int d4 = 0; d4 < 8; ++d4) dst[d4] = src[d4];
            } else {
                const float4 z = {0.f, 0.f, 0.f, 0.f};
#pragma unroll
                for (int d4 = 0; d4 < 8; ++d4) dst[d4] = z;
            }
        }
        __syncthreads();

        if (lane < 49) {
            float s[32];
#pragma unroll
            for (int jj = 0; jj < 32; ++jj) {
                const float4* kr = (const float4*)Ks[jj];   // broadcast reads
                float p0 = 0.f, p1 = 0.f, p2 = 0.f, p3 = 0.f;
#pragma unroll
                for (int d4 = 0; d4 < 8; ++d4) {
                    const float4 kd = kr[d4];
                    p0 = fmaf(q[d4 * 4 + 0], kd.x, p0);
                    p1 = fmaf(q[d4 * 4 + 1], kd.y, p1);
                    p2 = fmaf(q[d4 * 4 + 2], kd.z, p2);
                    p3 = fmaf(q[d4 * 4 + 3], kd.w, p3);
                }
                s[jj] = (p0 + p1) + (p2 + p3);
            }
            float mt = m;
#pragma unroll
            for (int jj = 0; jj < 32; ++jj) {
                if (t0 + jj >= NKEYS) s[jj] = -1e30f;   // mask tail
                mt = fmaxf(mt, s[jj]);
            }
            const float corr = __expf(m - mt);
            m = mt;
            l *= corr;
#pragma unroll
            for (int d = 0; d < 32; ++d) acc[d] *= corr;
#pragma unroll
            for (int jj = 0; jj < 32; ++jj) {
                const float p = __expf(s[jj] - mt);
                l += p;
                const float4* vr = (const float4*)Vs[jj];
#pragma unroll
                for (int d4 = 0; d4 < 8; ++d4) {
                    const float4 vv = vr[d4];
                    acc[d4 * 4 + 0] = fmaf(p, vv.x, acc[d4 * 4 + 0]);
                    acc[d4 * 4 + 1] = fmaf(p, vv.y, acc[d4 * 4 + 1]);
                    acc[d4 * 4 + 2] = fmaf(p, vv.z, acc[d4 * 4 + 2]);
                    acc[d4 * 4 + 3] = fmaf(p, vv.w, acc[d4 * 4 + 3]);
                }
            }
        }
        __syncthreads();
    }

    if (lane < 49) {
        const float inv = 1.0f / l;
        float* op = out + (size_t)(w * 49 + lane) * 256 + h * 32;
#pragma unroll
        for (int d4 = 0; d4 < 8; ++d4) {
            float4 o;
            o.x = acc[d4 * 4 + 0] * inv;
            o.y = acc[d4 * 4 + 1] * inv;
            o.z = acc[d4 * 4 + 2] * inv;
            o.w = acc[d4 * 4 + 3] * inv;
            *(float4*)(op + d4 * 4) = o;
        }
    }
}

// ---------------- launch ----------------
extern "C" void kernel_launch(void* const* d_in, const int* in_sizes, int n_in,
                              void* d_out, int out_size, void* d_ws, size_t ws_size,
                              hipStream_t stream)
{
    const float* x      = (const float*)d_in[0];
    const float* pool0  = (const float*)d_in[1];
    const float* clip1  = (const float*)d_in[2];
    const float* clip2  = (const float*)d_in[3];
    const float* clip3  = (const float*)d_in[4];
    const float* qkv_w  = (const float*)d_in[5];
    const float* qkv_b  = (const float*)d_in[6];
    const float* proj_w = (const float*)d_in[7];
    const float* proj_b = (const float*)d_in[8];
    float* out = (float*)d_out;

    float* ws   = (float*)d_ws;
    float* qkv  = ws;                          // 25088*768
    float* kv1  = qkv + 25088ull * 768;        // 25088*512
    float* kv2  = kv1 + 25088ull * 512;        // 12800*512
    float* kv3  = kv2 + 12800ull * 512;        //  4608*512
    float* attn = kv3 + 4608ull * 512;         // 25088*256

    const dim3 blk(256);
    // x -> qkv (q|k|v).  M=25088 (/128=196), N=768 (/128=6)
    gemm_bias_kernel<<<dim3(768 / 128, 25088 / 128), blk, 0, stream>>>(
        x, qkv_w, 768, qkv_b, qkv, 768);
    // clips -> k|v only (cols 256..768).  N=512 (/128=4)
    gemm_bias_kernel<<<dim3(512 / 128, 25088 / 128), blk, 0, stream>>>(
        clip1, qkv_w + 256, 768, qkv_b + 256, kv1, 512);
    gemm_bias_kernel<<<dim3(512 / 128, 12800 / 128), blk, 0, stream>>>(
        clip2, qkv_w + 256, 768, qkv_b + 256, kv2, 512);
    gemm_bias_kernel<<<dim3(512 / 128, 4608 / 128), blk, 0, stream>>>(
        clip3, qkv_w + 256, 768, qkv_b + 256, kv3, 512);
    // attention
    attn_kernel<<<dim3(512 * 8), dim3(64), 0, stream>>>(
        qkv, pool0, kv1, kv2, kv3, attn);
    // projection.  N=256 (/128=2)
    gemm_bias_kernel<<<dim3(256 / 128, 25088 / 128), blk, 0, stream>>>(
        attn, proj_w, 256, proj_b, out, 256);
}

// Round 3
// 649.217 us; speedup vs baseline: 1.5799x; 1.5799x over previous
//
#include <hip/hip_runtime.h>

// CffmTransformerBlock3d3 — round 3: bf16-MFMA flash attention, fp32 GEMMs.
//
// Attention: one 256-thread block (4 waves) per (window, head).
//   gather: K[384][40]bf16, Vt[32][768B]bf16 (phi-ordered cols, XOR-swizzled),
//           Q[64][32]bf16, pads zeroed.
//   QK^T:  S = Q*K^T via mfma_f32_16x16x32_bf16 (A=Q rows, B=K rows; both
//          k-contiguous 16B LDS reads). Wave ww owns keys [ww*96, ww*96+96).
//   softmax: per-(rb,r) row partials, shfl_xor butterfly over 16 lanes,
//          cross-wave combine via LDS stats.
//   PV:    P chunks staged per-wave in phi-local [64][80B] buffer (packed b32
//          writes), A=P, B=Vt rows; 3 chunk-MFMAs accumulate fp32.
//   reduce: O partials summed via LDS, divided by row-sum, stored fp32.

#define K_DIM 256
#define NKEYS 377

typedef unsigned int u32;
typedef unsigned short u16;
typedef __attribute__((ext_vector_type(8))) short bf16x8;
typedef __attribute__((ext_vector_type(4))) float f32x4;

__device__ __forceinline__ u16 f2bf(float f) {
    u32 b = __float_as_uint(f);
    b += 0x7FFFu + ((b >> 16) & 1u);
    return (u16)(b >> 16);
}
__device__ __forceinline__ u32 pack2(float lo, float hi) {
    return (u32)f2bf(lo) | ((u32)f2bf(hi) << 16);
}

// ---------------- GEMM: C[M,N] = A[M,256] @ W[256,N] + bias ----------------
// 128x128 block tile, 256 threads, 8x8 per-thread microtile, K chunks of 16.
__global__ __launch_bounds__(256)
void gemm_bias_kernel(const float* __restrict__ A,
                      const float* __restrict__ W, int ldw,
                      const float* __restrict__ bias,
                      float* __restrict__ C, int ldc)
{
    __shared__ float As[16][132];
    __shared__ float Ws[16][132];

    const int tid = threadIdx.x;
    const int n0 = blockIdx.x * 128;
    const int m0 = blockIdx.y * 128;

    const int am = tid >> 1;
    const int ak = (tid & 1) << 3;
    const int wk = tid >> 4;
    const int wn = (tid & 15) << 3;
    const int tm = tid >> 4;
    const int tn = tid & 15;

    float acc[8][8];
#pragma unroll
    for (int i = 0; i < 8; ++i)
#pragma unroll
        for (int j = 0; j < 8; ++j) acc[i][j] = 0.f;

    const float* Arow = A + (size_t)(m0 + am) * K_DIM + ak;
    const float* Wrow = W + (size_t)wk * ldw + n0 + wn;

    for (int k0 = 0; k0 < K_DIM; k0 += 16) {
        const float4 av0 = *(const float4*)(Arow + k0);
        const float4 av1 = *(const float4*)(Arow + k0 + 4);
        const float4 wv0 = *(const float4*)(Wrow + (size_t)k0 * ldw);
        const float4 wv1 = *(const float4*)(Wrow + (size_t)k0 * ldw + 4);
        __syncthreads();
        As[ak + 0][am] = av0.x;
        As[ak + 1][am] = av0.y;
        As[ak + 2][am] = av0.z;
        As[ak + 3][am] = av0.w;
        As[ak + 4][am] = av1.x;
        As[ak + 5][am] = av1.y;
        As[ak + 6][am] = av1.z;
        As[ak + 7][am] = av1.w;
        *(float4*)&Ws[wk][wn]     = wv0;
        *(float4*)&Ws[wk][wn + 4] = wv1;
        __syncthreads();
#pragma unroll
        for (int k = 0; k < 16; ++k) {
            float a[8], w[8];
            *(float4*)&a[0] = *(const float4*)&As[k][tm << 3];
            *(float4*)&a[4] = *(const float4*)&As[k][(tm << 3) + 4];
            *(float4*)&w[0] = *(const float4*)&Ws[k][tn << 3];
            *(float4*)&w[4] = *(const float4*)&Ws[k][(tn << 3) + 4];
#pragma unroll
            for (int i = 0; i < 8; ++i)
#pragma unroll
                for (int j = 0; j < 8; ++j)
                    acc[i][j] = fmaf(a[i], w[j], acc[i][j]);
        }
    }

    float b[8];
    *(float4*)&b[0] = *(const float4*)(bias + n0 + (tn << 3));
    *(float4*)&b[4] = *(const float4*)(bias + n0 + (tn << 3) + 4);
#pragma unroll
    for (int i = 0; i < 8; ++i) {
        float* crow = C + (size_t)(m0 + (tm << 3) + i) * ldc + n0 + (tn << 3);
        float4 o0, o1;
        o0.x = acc[i][0] + b[0];
        o0.y = acc[i][1] + b[1];
        o0.z = acc[i][2] + b[2];
        o0.w = acc[i][3] + b[3];
        o1.x = acc[i][4] + b[4];
        o1.y = acc[i][5] + b[5];
        o1.z = acc[i][6] + b[6];
        o1.w = acc[i][7] + b[7];
        *(float4*)crow       = o0;
        *(float4*)(crow + 4) = o1;
    }
}

// ---------------- MFMA attention ----------------
// LDS layout (bytes):
//  [0,24576)      Vt   32 rows x 768B (bf16, phi-ordered key cols, XOR swz)
//  [24576,55296)  K    384 rows x 80B (bf16)          | reused: Pbuf 4x64x80B
//  [55296,59392)  Q    64 rows x 64B (bf16)           |          [24576,45056)
//  [59392,60416)  SMAX [4][64] f32
//  [60416,61440)  SSUM [4][64] f32
//  [61440,61696)  GMAX [64] f32
//  [0,32768)      ORED [4][64][32] f32 (after Vt/Pbuf dead)
#define VT_OFF   0
#define KL_OFF   24576
#define Q_OFF    55296
#define SMAX_OFF 59392
#define SSUM_OFF 60416
#define GMAX_OFF 61440
#define PBUF_OFF 24576
#define ORED_OFF 0
#define LDS_SZ   61696

__global__ __launch_bounds__(256)
void attn_kernel(const float* __restrict__ qkv,    // [25088, 768] q|k|v
                 const float* __restrict__ pool0,  // [512 * 12544]
                 const float* __restrict__ kv1,    // [25088, 512] k|v
                 const float* __restrict__ kv2,    // [12800, 512]
                 const float* __restrict__ kv3,    // [4608, 512]
                 float* __restrict__ out)          // [25088, 256]
{
    __shared__ __align__(16) char smem[LDS_SZ];

    const int wh  = blockIdx.x;
    const int win = wh >> 3, h = wh & 7;
    const int bb  = win >> 8, wi = (win >> 4) & 15, wj = win & 15;
    const int tid = threadIdx.x;
    const int lane = tid & 63, ww = tid >> 6;
    const int l15 = lane & 15, g = lane >> 4;

    // ---------------- gather ----------------
    if (tid < 192) {
        // Vt columns 2*tid, 2*tid+1  <->  keys keyA, keyA+16
        const int j0   = tid * 2;
        const int gw   = j0 / 96, rem = j0 % 96;
        const int gk   = rem / 32, gl = (rem % 32) >> 1;
        const int keyA = (gw * 6 + gk * 2) * 16 + gl;
        float vbuf[2][32];
#pragma unroll
        for (int s = 0; s < 2; ++s) {
            const int key = keyA + s * 16;
            if (key < NKEYS) {
                const float *kp, *vp;
                if (key < 245) {
                    int aa, cc, hh, ww2;
                    if (key < 49) {
                        aa = key / 7; cc = key % 7;
                        hh = wi * 7 + aa; ww2 = wj * 7 + cc;
                    } else {
                        const int u = key - 49, si = u / 49, rr = u % 49;
                        aa = rr / 7; cc = rr % 7;
                        const int sh = (si < 2) ? -3 : 3;
                        const int sw = (si & 1) ? 3 : -3;
                        hh  = (wi * 7 + aa - sh + 112) % 112;
                        ww2 = (wj * 7 + cc - sw + 112) % 112;
                    }
                    const int row = (bb * 112 + hh) * 112 + ww2;
                    kp = qkv + (size_t)row * 768 + 256 + h * 32;
                    vp = qkv + (size_t)row * 768 + 512 + h * 32;
                } else if (key < 294) {
                    const float* p = pool0 + (size_t)win * 12544 + h * 1568 + (key - 245) * 32;
                    kp = p; vp = p;
                } else if (key < 343) {
                    const float* p = kv1 + (size_t)(win * 49 + key - 294) * 512 + h * 32;
                    kp = p; vp = p + 256;
                } else if (key < 368) {
                    const float* p = kv2 + (size_t)(win * 25 + key - 343) * 512 + h * 32;
                    kp = p; vp = p + 256;
                } else {
                    const float* p = kv3 + (size_t)(win * 9 + key - 368) * 512 + h * 32;
                    kp = p; vp = p + 256;
                }
                const float4* kp4 = (const float4*)kp;
                const float4* vp4 = (const float4*)vp;
#pragma unroll
                for (int jq = 0; jq < 4; ++jq) {
                    const float4 x0 = kp4[2 * jq], x1 = kp4[2 * jq + 1];
                    bf16x8 t;
                    t[0] = (short)f2bf(x0.x); t[1] = (short)f2bf(x0.y);
                    t[2] = (short)f2bf(x0.z); t[3] = (short)f2bf(x0.w);
                    t[4] = (short)f2bf(x1.x); t[5] = (short)f2bf(x1.y);
                    t[6] = (short)f2bf(x1.z); t[7] = (short)f2bf(x1.w);
                    *(bf16x8*)(smem + KL_OFF + key * 80 + jq * 16) = t;
                }
#pragma unroll
                for (int jq = 0; jq < 8; ++jq) {
                    const float4 v = vp4[jq];
                    vbuf[s][4 * jq + 0] = v.x; vbuf[s][4 * jq + 1] = v.y;
                    vbuf[s][4 * jq + 2] = v.z; vbuf[s][4 * jq + 3] = v.w;
                }
            } else {
                const bf16x8 z = {0, 0, 0, 0, 0, 0, 0, 0};
#pragma unroll
                for (int jq = 0; jq < 4; ++jq)
                    *(bf16x8*)(smem + KL_OFF + key * 80 + jq * 16) = z;
#pragma unroll
                for (int d = 0; d < 32; ++d) vbuf[s][d] = 0.f;
            }
        }
#pragma unroll
        for (int d = 0; d < 32; ++d) {
            int byte = d * 768 + tid * 4;
            byte ^= (d & 7) << 4;
            *(u32*)(smem + VT_OFF + byte) = pack2(vbuf[0][d], vbuf[1][d]);
        }
    } else {
        const int q = tid - 192;            // 0..63
        if (q < 49) {
            const int aa = q / 7, cc = q % 7;
            const int row = (bb * 112 + wi * 7 + aa) * 112 + wj * 7 + cc;
            const float4* qp = (const float4*)(qkv + (size_t)row * 768 + h * 32);
            const float scale = 0.17677669529663687f;   // 32^-0.5
#pragma unroll
            for (int jq = 0; jq < 4; ++jq) {
                const float4 x0 = qp[2 * jq], x1 = qp[2 * jq + 1];
                bf16x8 t;
                t[0] = (short)f2bf(x0.x * scale); t[1] = (short)f2bf(x0.y * scale);
                t[2] = (short)f2bf(x0.z * scale); t[3] = (short)f2bf(x0.w * scale);
                t[4] = (short)f2bf(x1.x * scale); t[5] = (short)f2bf(x1.y * scale);
                t[6] = (short)f2bf(x1.z * scale); t[7] = (short)f2bf(x1.w * scale);
                *(bf16x8*)(smem + Q_OFF + q * 64 + jq * 16) = t;
            }
        } else {
            const bf16x8 z = {0, 0, 0, 0, 0, 0, 0, 0};
#pragma unroll
            for (int jq = 0; jq < 4; ++jq)
                *(bf16x8*)(smem + Q_OFF + q * 64 + jq * 16) = z;
        }
    }
    __syncthreads();   // B0: gather complete

    // ---------------- QK^T ----------------
    bf16x8 aq[4];
#pragma unroll
    for (int rb = 0; rb < 4; ++rb)
        aq[rb] = *(const bf16x8*)(smem + Q_OFF + (16 * rb + l15) * 64 + g * 16);

    f32x4 S[4][6];
    const f32x4 z4 = {0.f, 0.f, 0.f, 0.f};
#pragma unroll
    for (int c = 0; c < 6; ++c) {
        const int key = (ww * 6 + c) * 16 + l15;
        const bf16x8 bk = *(const bf16x8*)(smem + KL_OFF + key * 80 + g * 16);
#pragma unroll
        for (int rb = 0; rb < 4; ++rb)
            S[rb][c] = __builtin_amdgcn_mfma_f32_16x16x32_bf16(aq[rb], bk, z4, 0, 0, 0);
    }

    // ---------------- row max (strip) ----------------
    float mx[4][4];
#pragma unroll
    for (int rb = 0; rb < 4; ++rb)
#pragma unroll
        for (int r = 0; r < 4; ++r) {
            float v = S[rb][0][r];
#pragma unroll
            for (int c = 1; c < 6; ++c) v = fmaxf(v, S[rb][c][r]);
            mx[rb][r] = v;
        }
#pragma unroll
    for (int mvar = 1; mvar <= 8; mvar <<= 1)
#pragma unroll
        for (int rb = 0; rb < 4; ++rb)
#pragma unroll
            for (int r = 0; r < 4; ++r)
                mx[rb][r] = fmaxf(mx[rb][r], __shfl_xor(mx[rb][r], mvar, 64));
    {
        const int drb = l15 >> 2, dr = l15 & 3;
        const int row = 16 * drb + 4 * g + dr;
        *(float*)(smem + SMAX_OFF + (ww * 64 + row) * 4) = mx[drb][dr];
    }
    __syncthreads();   // B1: stats_max ready; Q/K reads done

    if (tid < 64) {
        float gm = *(const float*)(smem + SMAX_OFF + tid * 4);
#pragma unroll
        for (int wv = 1; wv < 4; ++wv)
            gm = fmaxf(gm, *(const float*)(smem + SMAX_OFF + (wv * 64 + tid) * 4));
        *(float*)(smem + GMAX_OFF + tid * 4) = gm;
    }
    __syncthreads();   // B2: gmax ready

    // ---------------- P = exp(S - gmax), row sums ----------------
    float gm[4][4];
#pragma unroll
    for (int rb = 0; rb < 4; ++rb)
#pragma unroll
        for (int r = 0; r < 4; ++r)
            gm[rb][r] = *(const float*)(smem + GMAX_OFF + (16 * rb + 4 * g + r) * 4);

    float sm[4][4];
#pragma unroll
    for (int rb = 0; rb < 4; ++rb)
#pragma unroll
        for (int r = 0; r < 4; ++r) sm[rb][r] = 0.f;

#pragma unroll
    for (int c = 0; c < 6; ++c) {
        const bool tail = (ww == 3) && (c == 5) && (l15 >= 9);   // keys >= 377
#pragma unroll
        for (int rb = 0; rb < 4; ++rb) {
            f32x4 p;
#pragma unroll
            for (int r = 0; r < 4; ++r) {
                const float e = tail ? 0.f : __expf(S[rb][c][r] - gm[rb][r]);
                p[r] = e;
                sm[rb][r] += e;
            }
            S[rb][c] = p;   // S now holds P
        }
    }
#pragma unroll
    for (int mvar = 1; mvar <= 8; mvar <<= 1)
#pragma unroll
        for (int rb = 0; rb < 4; ++rb)
#pragma unroll
            for (int r = 0; r < 4; ++r)
                sm[rb][r] += __shfl_xor(sm[rb][r], mvar, 64);
    {
        const int drb = l15 >> 2, dr = l15 & 3;
        const int row = 16 * drb + 4 * g + dr;
        *(float*)(smem + SSUM_OFF + (ww * 64 + row) * 4) = sm[drb][dr];
    }

    // ---------------- PV (per-wave chunks of 32 keys) ----------------
    f32x4 O_[4][2];
#pragma unroll
    for (int rb = 0; rb < 4; ++rb) { O_[rb][0] = z4; O_[rb][1] = z4; }

    char* pbuf = smem + PBUF_OFF + ww * 5120;   // per-wave [64][80B]
#pragma unroll
    for (int kcl = 0; kcl < 3; ++kcl) {
        // stage own P chunk: phi-local slot = l15*2 + parity
#pragma unroll
        for (int rb = 0; rb < 4; ++rb)
#pragma unroll
            for (int r = 0; r < 4; ++r) {
                const int row = 16 * rb + 4 * g + r;
                *(u32*)(pbuf + row * 80 + l15 * 4) =
                    pack2(S[rb][2 * kcl][r], S[rb][2 * kcl + 1][r]);
            }
        bf16x8 bv[2];
#pragma unroll
        for (int nc = 0; nc < 2; ++nc) {
            const int dim = 16 * nc + l15;
            int byte = dim * 768 + ww * 192 + kcl * 64 + g * 16;
            byte ^= (dim & 7) << 4;
            bv[nc] = *(const bf16x8*)(smem + VT_OFF + byte);
        }
#pragma unroll
        for (int rb = 0; rb < 4; ++rb) {
            const bf16x8 ap = *(const bf16x8*)(pbuf + (16 * rb + l15) * 80 + g * 16);
            O_[rb][0] = __builtin_amdgcn_mfma_f32_16x16x32_bf16(ap, bv[0], O_[rb][0], 0, 0, 0);
            O_[rb][1] = __builtin_amdgcn_mfma_f32_16x16x32_bf16(ap, bv[1], O_[rb][1], 0, 0, 0);
        }
    }
    __syncthreads();   // B3: Vt / Pbuf dead

    // ---------------- cross-wave O reduction ----------------
#pragma unroll
    for (int rb = 0; rb < 4; ++rb)
#pragma unroll
        for (int nc = 0; nc < 2; ++nc)
#pragma unroll
            for (int r = 0; r < 4; ++r) {
                const int row = 16 * rb + 4 * g + r;
                const int col = 16 * nc + l15;
                *(float*)(smem + ORED_OFF + ((ww * 64 + row) * 32 + col) * 4) = O_[rb][nc][r];
            }
    __syncthreads();   // B4: O_red ready

    {
        const int row = tid >> 2, d0 = (tid & 3) * 8;
        if (row < 49) {
            float lt = 0.f;
#pragma unroll
            for (int wv = 0; wv < 4; ++wv)
                lt += *(const float*)(smem + SSUM_OFF + (wv * 64 + row) * 4);
            const float inv = 1.0f / lt;
            float o[8];
#pragma unroll
            for (int i = 0; i < 8; ++i) {
                float s = 0.f;
#pragma unroll
                for (int wv = 0; wv < 4; ++wv)
                    s += *(const float*)(smem + ORED_OFF + ((wv * 64 + row) * 32 + d0 + i) * 4);
                o[i] = s * inv;
            }
            float* dst = out + (size_t)(win * 49 + row) * 256 + h * 32 + d0;
            float4 o0 = {o[0], o[1], o[2], o[3]};
            float4 o1 = {o[4], o[5], o[6], o[7]};
            *(float4*)dst       = o0;
            *(float4*)(dst + 4) = o1;
        }
    }
}

// ---------------- launch ----------------
extern "C" void kernel_launch(void* const* d_in, const int* in_sizes, int n_in,
                              void* d_out, int out_size, void* d_ws, size_t ws_size,
                              hipStream_t stream)
{
    const float* x      = (const float*)d_in[0];
    const float* pool0  = (const float*)d_in[1];
    const float* clip1  = (const float*)d_in[2];
    const float* clip2  = (const float*)d_in[3];
    const float* clip3  = (const float*)d_in[4];
    const float* qkv_w  = (const float*)d_in[5];
    const float* qkv_b  = (const float*)d_in[6];
    const float* proj_w = (const float*)d_in[7];
    const float* proj_b = (const float*)d_in[8];
    float* out = (float*)d_out;

    float* ws   = (float*)d_ws;
    float* qkv  = ws;                          // 25088*768
    float* kv1  = qkv + 25088ull * 768;        // 25088*512
    float* kv2  = kv1 + 25088ull * 512;        // 12800*512
    float* kv3  = kv2 + 12800ull * 512;        //  4608*512
    float* attn = kv3 + 4608ull * 512;         // 25088*256

    const dim3 blk(256);
    gemm_bias_kernel<<<dim3(768 / 128, 25088 / 128), blk, 0, stream>>>(
        x, qkv_w, 768, qkv_b, qkv, 768);
    gemm_bias_kernel<<<dim3(512 / 128, 25088 / 128), blk, 0, stream>>>(
        clip1, qkv_w + 256, 768, qkv_b + 256, kv1, 512);
    gemm_bias_kernel<<<dim3(512 / 128, 12800 / 128), blk, 0, stream>>>(
        clip2, qkv_w + 256, 768, qkv_b + 256, kv2, 512);
    gemm_bias_kernel<<<dim3(512 / 128, 4608 / 128), blk, 0, stream>>>(
        clip3, qkv_w + 256, 768, qkv_b + 256, kv3, 512);
    attn_kernel<<<dim3(512 * 8), dim3(256), 0, stream>>>(
        qkv, pool0, kv1, kv2, kv3, attn);
    gemm_bias_kernel<<<dim3(256 / 128, 25088 / 128), blk, 0, stream>>>(
        attn, proj_w, 256, proj_b, out, 256);
}

// Round 4
// 383.758 us; speedup vs baseline: 2.6728x; 1.6917x over previous
//
#include <hip/hip_runtime.h>
#include <hip/hip_bf16.h>

// CffmTransformerBlock3d3 — round 4: bf16-MFMA GEMMs (m97 structure),
// bf16-MFMA flash attention (unchanged from r3).
//
//  wprep : transpose+convert qkv_w -> Wt_qkv[768][256] bf16, proj_w -> Wt_proj.
//  GEMM  : C[M,N] = A[M,256] @ W + bias.  128x128 tile, 4 waves, 16x16x32
//          bf16 MFMA, A converted fp32->bf16 during staging, B staged bf16.
//          fp32 accumulate + fp32 outputs (interfaces unchanged).
//  attn  : one 256-thread block per (window, head), QK^T/PV via MFMA.

#define K_DIM 256
#define NKEYS 377

typedef unsigned int u32;
typedef unsigned short u16;
typedef __attribute__((ext_vector_type(8))) short bf16x8;
typedef __attribute__((ext_vector_type(4))) float f32x4;

__device__ __forceinline__ u16 f2bf(float f) {
    u32 b = __float_as_uint(f);
    b += 0x7FFFu + ((b >> 16) & 1u);
    return (u16)(b >> 16);
}
__device__ __forceinline__ u32 pack2(float lo, float hi) {
    return (u32)f2bf(lo) | ((u32)f2bf(hi) << 16);
}
// 8 f32 -> bf16x8 via v_cvt_pk_bf16_f32 (compiler generates from scalar casts)
__device__ __forceinline__ bf16x8 cvt8(float4 x, float4 y) {
    union { bf16x8 v; __hip_bfloat162 h[4]; } un;
    un.h[0] = __float22bfloat162_rn(make_float2(x.x, x.y));
    un.h[1] = __float22bfloat162_rn(make_float2(x.z, x.w));
    un.h[2] = __float22bfloat162_rn(make_float2(y.x, y.y));
    un.h[3] = __float22bfloat162_rn(make_float2(y.z, y.w));
    return un.v;
}

// ---------------- weight prep: Wt[n][k] = bf16(W[k][n]) ----------------
__global__ __launch_bounds__(256)
void wprep_kernel(const float* __restrict__ qkv_w,   // [256][768]
                  const float* __restrict__ proj_w,  // [256][256]
                  __hip_bfloat16* __restrict__ wq,   // [768][256]
                  __hip_bfloat16* __restrict__ wp)   // [256][256]
{
    const int n = blockIdx.x;
    const int k = threadIdx.x;
    if (n < 768) wq[n * 256 + k] = __float2bfloat16(qkv_w[k * 768 + n]);
    else         wp[(n - 768) * 256 + k] = __float2bfloat16(proj_w[k * 256 + (n - 768)]);
}

// ---------------- bf16 MFMA GEMM ----------------
// A[M][256] fp32 (cvt during staging), Bt[N][256] bf16 (K-contig rows),
// C[M][ldc] fp32 + bias.  Grid: (N/128, M/128), 256 threads.
__global__ __launch_bounds__(256)
void gemm_mfma_kernel(const float* __restrict__ A,
                      const __hip_bfloat16* __restrict__ Bt,
                      const float* __restrict__ bias,
                      float* __restrict__ C, int ldc)
{
    __shared__ __align__(16) short As[128][32];   // rows of 64 B
    __shared__ __align__(16) short Bs[128][32];

    const int tid = threadIdx.x;
    const int n0 = blockIdx.x * 128;
    const int m0 = blockIdx.y * 128;
    const int lane = tid & 63, wv = tid >> 6;
    const int wm = (wv >> 1) << 6;                // wave M offset (0/64)
    const int wn = (wv & 1) << 6;                 // wave N offset (0/64)
    const int l15 = lane & 15, g = lane >> 4;     // frag row / k-group

    const int sr = tid >> 1;                      // staging row 0..127
    const int sk = (tid & 1) << 4;                // k offset 0 or 16 (elements)

    const float* Ap = A + (size_t)(m0 + sr) * 256 + sk;
    const short* Bp = (const short*)Bt + (size_t)(n0 + sr) * 256 + sk;

    f32x4 acc[4][4];
    const f32x4 z4 = {0.f, 0.f, 0.f, 0.f};
#pragma unroll
    for (int i = 0; i < 4; ++i)
#pragma unroll
        for (int j = 0; j < 4; ++j) acc[i][j] = z4;

    // prologue: load K-tile 0
    float4 a0 = *(const float4*)(Ap + 0);
    float4 a1 = *(const float4*)(Ap + 4);
    float4 a2 = *(const float4*)(Ap + 8);
    float4 a3 = *(const float4*)(Ap + 12);
    bf16x8 b0 = *(const bf16x8*)(Bp + 0);
    bf16x8 b1 = *(const bf16x8*)(Bp + 8);

    for (int k0 = 0; k0 < 256; k0 += 32) {
        __syncthreads();   // previous compute done, LDS free
        *(bf16x8*)&As[sr][sk]     = cvt8(a0, a1);
        *(bf16x8*)&As[sr][sk + 8] = cvt8(a2, a3);
        *(bf16x8*)&Bs[sr][sk]     = b0;
        *(bf16x8*)&Bs[sr][sk + 8] = b1;
        if (k0 + 32 < 256) {   // prefetch next K-tile (overlaps with compute below)
            a0 = *(const float4*)(Ap + k0 + 32);
            a1 = *(const float4*)(Ap + k0 + 36);
            a2 = *(const float4*)(Ap + k0 + 40);
            a3 = *(const float4*)(Ap + k0 + 44);
            b0 = *(const bf16x8*)(Bp + k0 + 32);
            b1 = *(const bf16x8*)(Bp + k0 + 40);
        }
        __syncthreads();   // tile ready
        bf16x8 af[4], bfr[4];
#pragma unroll
        for (int rb = 0; rb < 4; ++rb)
            af[rb] = *(const bf16x8*)&As[wm + rb * 16 + l15][g << 3];
#pragma unroll
        for (int cb = 0; cb < 4; ++cb)
            bfr[cb] = *(const bf16x8*)&Bs[wn + cb * 16 + l15][g << 3];
#pragma unroll
        for (int rb = 0; rb < 4; ++rb)
#pragma unroll
            for (int cb = 0; cb < 4; ++cb)
                acc[rb][cb] = __builtin_amdgcn_mfma_f32_16x16x32_bf16(
                    af[rb], bfr[cb], acc[rb][cb], 0, 0, 0);
    }

    float bcol[4];
#pragma unroll
    for (int cb = 0; cb < 4; ++cb) bcol[cb] = bias[n0 + wn + cb * 16 + l15];
#pragma unroll
    for (int rb = 0; rb < 4; ++rb)
#pragma unroll
        for (int r = 0; r < 4; ++r) {
            const int m = m0 + wm + rb * 16 + (g << 2) + r;
            float* crow = C + (size_t)m * ldc + n0 + wn + l15;
#pragma unroll
            for (int cb = 0; cb < 4; ++cb)
                crow[cb * 16] = acc[rb][cb][r] + bcol[cb];
        }
}

// ---------------- MFMA attention (unchanged from r3) ----------------
#define VT_OFF   0
#define KL_OFF   24576
#define Q_OFF    55296
#define SMAX_OFF 59392
#define SSUM_OFF 60416
#define GMAX_OFF 61440
#define PBUF_OFF 24576
#define ORED_OFF 0
#define LDS_SZ   61696

__global__ __launch_bounds__(256)
void attn_kernel(const float* __restrict__ qkv,    // [25088, 768] q|k|v
                 const float* __restrict__ pool0,  // [512 * 12544]
                 const float* __restrict__ kv1,    // [25088, 512] k|v
                 const float* __restrict__ kv2,    // [12800, 512]
                 const float* __restrict__ kv3,    // [4608, 512]
                 float* __restrict__ out)          // [25088, 256]
{
    __shared__ __align__(16) char smem[LDS_SZ];

    const int wh  = blockIdx.x;
    const int win = wh >> 3, h = wh & 7;
    const int bb  = win >> 8, wi = (win >> 4) & 15, wj = win & 15;
    const int tid = threadIdx.x;
    const int lane = tid & 63, ww = tid >> 6;
    const int l15 = lane & 15, g = lane >> 4;

    // ---------------- gather ----------------
    if (tid < 192) {
        const int j0   = tid * 2;
        const int gw   = j0 / 96, rem = j0 % 96;
        const int gk   = rem / 32, gl = (rem % 32) >> 1;
        const int keyA = (gw * 6 + gk * 2) * 16 + gl;
        float vbuf[2][32];
#pragma unroll
        for (int s = 0; s < 2; ++s) {
            const int key = keyA + s * 16;
            if (key < NKEYS) {
                const float *kp, *vp;
                if (key < 245) {
                    int aa, cc, hh, ww2;
                    if (key < 49) {
                        aa = key / 7; cc = key % 7;
                        hh = wi * 7 + aa; ww2 = wj * 7 + cc;
                    } else {
                        const int u = key - 49, si = u / 49, rr = u % 49;
                        aa = rr / 7; cc = rr % 7;
                        const int sh = (si < 2) ? -3 : 3;
                        const int sw = (si & 1) ? 3 : -3;
                        hh  = (wi * 7 + aa - sh + 112) % 112;
                        ww2 = (wj * 7 + cc - sw + 112) % 112;
                    }
                    const int row = (bb * 112 + hh) * 112 + ww2;
                    kp = qkv + (size_t)row * 768 + 256 + h * 32;
                    vp = qkv + (size_t)row * 768 + 512 + h * 32;
                } else if (key < 294) {
                    const float* p = pool0 + (size_t)win * 12544 + h * 1568 + (key - 245) * 32;
                    kp = p; vp = p;
                } else if (key < 343) {
                    const float* p = kv1 + (size_t)(win * 49 + key - 294) * 512 + h * 32;
                    kp = p; vp = p + 256;
                } else if (key < 368) {
                    const float* p = kv2 + (size_t)(win * 25 + key - 343) * 512 + h * 32;
                    kp = p; vp = p + 256;
                } else {
                    const float* p = kv3 + (size_t)(win * 9 + key - 368) * 512 + h * 32;
                    kp = p; vp = p + 256;
                }
                const float4* kp4 = (const float4*)kp;
                const float4* vp4 = (const float4*)vp;
#pragma unroll
                for (int jq = 0; jq < 4; ++jq) {
                    const float4 x0 = kp4[2 * jq], x1 = kp4[2 * jq + 1];
                    bf16x8 t;
                    t[0] = (short)f2bf(x0.x); t[1] = (short)f2bf(x0.y);
                    t[2] = (short)f2bf(x0.z); t[3] = (short)f2bf(x0.w);
                    t[4] = (short)f2bf(x1.x); t[5] = (short)f2bf(x1.y);
                    t[6] = (short)f2bf(x1.z); t[7] = (short)f2bf(x1.w);
                    *(bf16x8*)(smem + KL_OFF + key * 80 + jq * 16) = t;
                }
#pragma unroll
                for (int jq = 0; jq < 8; ++jq) {
                    const float4 v = vp4[jq];
                    vbuf[s][4 * jq + 0] = v.x; vbuf[s][4 * jq + 1] = v.y;
                    vbuf[s][4 * jq + 2] = v.z; vbuf[s][4 * jq + 3] = v.w;
                }
            } else {
                const bf16x8 z = {0, 0, 0, 0, 0, 0, 0, 0};
#pragma unroll
                for (int jq = 0; jq < 4; ++jq)
                    *(bf16x8*)(smem + KL_OFF + key * 80 + jq * 16) = z;
#pragma unroll
                for (int d = 0; d < 32; ++d) vbuf[s][d] = 0.f;
            }
        }
#pragma unroll
        for (int d = 0; d < 32; ++d) {
            int byte = d * 768 + tid * 4;
            byte ^= (d & 7) << 4;
            *(u32*)(smem + VT_OFF + byte) = pack2(vbuf[0][d], vbuf[1][d]);
        }
    } else {
        const int q = tid - 192;
        if (q < 49) {
            const int aa = q / 7, cc = q % 7;
            const int row = (bb * 112 + wi * 7 + aa) * 112 + wj * 7 + cc;
            const float4* qp = (const float4*)(qkv + (size_t)row * 768 + h * 32);
            const float scale = 0.17677669529663687f;
#pragma unroll
            for (int jq = 0; jq < 4; ++jq) {
                const float4 x0 = qp[2 * jq], x1 = qp[2 * jq + 1];
                bf16x8 t;
                t[0] = (short)f2bf(x0.x * scale); t[1] = (short)f2bf(x0.y * scale);
                t[2] = (short)f2bf(x0.z * scale); t[3] = (short)f2bf(x0.w * scale);
                t[4] = (short)f2bf(x1.x * scale); t[5] = (short)f2bf(x1.y * scale);
                t[6] = (short)f2bf(x1.z * scale); t[7] = (short)f2bf(x1.w * scale);
                *(bf16x8*)(smem + Q_OFF + q * 64 + jq * 16) = t;
            }
        } else {
            const bf16x8 z = {0, 0, 0, 0, 0, 0, 0, 0};
#pragma unroll
            for (int jq = 0; jq < 4; ++jq)
                *(bf16x8*)(smem + Q_OFF + q * 64 + jq * 16) = z;
        }
    }
    __syncthreads();   // B0

    bf16x8 aq[4];
#pragma unroll
    for (int rb = 0; rb < 4; ++rb)
        aq[rb] = *(const bf16x8*)(smem + Q_OFF + (16 * rb + l15) * 64 + g * 16);

    f32x4 S[4][6];
    const f32x4 z4 = {0.f, 0.f, 0.f, 0.f};
#pragma unroll
    for (int c = 0; c < 6; ++c) {
        const int key = (ww * 6 + c) * 16 + l15;
        const bf16x8 bk = *(const bf16x8*)(smem + KL_OFF + key * 80 + g * 16);
#pragma unroll
        for (int rb = 0; rb < 4; ++rb)
            S[rb][c] = __builtin_amdgcn_mfma_f32_16x16x32_bf16(aq[rb], bk, z4, 0, 0, 0);
    }

    float mx[4][4];
#pragma unroll
    for (int rb = 0; rb < 4; ++rb)
#pragma unroll
        for (int r = 0; r < 4; ++r) {
            float v = S[rb][0][r];
#pragma unroll
            for (int c = 1; c < 6; ++c) v = fmaxf(v, S[rb][c][r]);
            mx[rb][r] = v;
        }
#pragma unroll
    for (int mvar = 1; mvar <= 8; mvar <<= 1)
#pragma unroll
        for (int rb = 0; rb < 4; ++rb)
#pragma unroll
            for (int r = 0; r < 4; ++r)
                mx[rb][r] = fmaxf(mx[rb][r], __shfl_xor(mx[rb][r], mvar, 64));
    {
        const int drb = l15 >> 2, dr = l15 & 3;
        const int row = 16 * drb + 4 * g + dr;
        *(float*)(smem + SMAX_OFF + (ww * 64 + row) * 4) = mx[drb][dr];
    }
    __syncthreads();   // B1

    if (tid < 64) {
        float gm = *(const float*)(smem + SMAX_OFF + tid * 4);
#pragma unroll
        for (int wv2 = 1; wv2 < 4; ++wv2)
            gm = fmaxf(gm, *(const float*)(smem + SMAX_OFF + (wv2 * 64 + tid) * 4));
        *(float*)(smem + GMAX_OFF + tid * 4) = gm;
    }
    __syncthreads();   // B2

    float gm[4][4];
#pragma unroll
    for (int rb = 0; rb < 4; ++rb)
#pragma unroll
        for (int r = 0; r < 4; ++r)
            gm[rb][r] = *(const float*)(smem + GMAX_OFF + (16 * rb + 4 * g + r) * 4);

    float sm[4][4];
#pragma unroll
    for (int rb = 0; rb < 4; ++rb)
#pragma unroll
        for (int r = 0; r < 4; ++r) sm[rb][r] = 0.f;

#pragma unroll
    for (int c = 0; c < 6; ++c) {
        const bool tail = (ww == 3) && (c == 5) && (l15 >= 9);
#pragma unroll
        for (int rb = 0; rb < 4; ++rb) {
            f32x4 p;
#pragma unroll
            for (int r = 0; r < 4; ++r) {
                const float e = tail ? 0.f : __expf(S[rb][c][r] - gm[rb][r]);
                p[r] = e;
                sm[rb][r] += e;
            }
            S[rb][c] = p;
        }
    }
#pragma unroll
    for (int mvar = 1; mvar <= 8; mvar <<= 1)
#pragma unroll
        for (int rb = 0; rb < 4; ++rb)
#pragma unroll
            for (int r = 0; r < 4; ++r)
                sm[rb][r] += __shfl_xor(sm[rb][r], mvar, 64);
    {
        const int drb = l15 >> 2, dr = l15 & 3;
        const int row = 16 * drb + 4 * g + dr;
        *(float*)(smem + SSUM_OFF + (ww * 64 + row) * 4) = sm[drb][dr];
    }

    f32x4 O_[4][2];
#pragma unroll
    for (int rb = 0; rb < 4; ++rb) { O_[rb][0] = z4; O_[rb][1] = z4; }

    char* pbuf = smem + PBUF_OFF + ww * 5120;
#pragma unroll
    for (int kcl = 0; kcl < 3; ++kcl) {
#pragma unroll
        for (int rb = 0; rb < 4; ++rb)
#pragma unroll
            for (int r = 0; r < 4; ++r) {
                const int row = 16 * rb + 4 * g + r;
                *(u32*)(pbuf + row * 80 + l15 * 4) =
                    pack2(S[rb][2 * kcl][r], S[rb][2 * kcl + 1][r]);
            }
        bf16x8 bv[2];
#pragma unroll
        for (int nc = 0; nc < 2; ++nc) {
            const int dim = 16 * nc + l15;
            int byte = dim * 768 + ww * 192 + kcl * 64 + g * 16;
            byte ^= (dim & 7) << 4;
            bv[nc] = *(const bf16x8*)(smem + VT_OFF + byte);
        }
#pragma unroll
        for (int rb = 0; rb < 4; ++rb) {
            const bf16x8 ap = *(const bf16x8*)(pbuf + (16 * rb + l15) * 80 + g * 16);
            O_[rb][0] = __builtin_amdgcn_mfma_f32_16x16x32_bf16(ap, bv[0], O_[rb][0], 0, 0, 0);
            O_[rb][1] = __builtin_amdgcn_mfma_f32_16x16x32_bf16(ap, bv[1], O_[rb][1], 0, 0, 0);
        }
    }
    __syncthreads();   // B3

#pragma unroll
    for (int rb = 0; rb < 4; ++rb)
#pragma unroll
        for (int nc = 0; nc < 2; ++nc)
#pragma unroll
            for (int r = 0; r < 4; ++r) {
                const int row = 16 * rb + 4 * g + r;
                const int col = 16 * nc + l15;
                *(float*)(smem + ORED_OFF + ((ww * 64 + row) * 32 + col) * 4) = O_[rb][nc][r];
            }
    __syncthreads();   // B4

    {
        const int row = tid >> 2, d0 = (tid & 3) * 8;
        if (row < 49) {
            float lt = 0.f;
#pragma unroll
            for (int wv2 = 0; wv2 < 4; ++wv2)
                lt += *(const float*)(smem + SSUM_OFF + (wv2 * 64 + row) * 4);
            const float inv = 1.0f / lt;
            float o[8];
#pragma unroll
            for (int i = 0; i < 8; ++i) {
                float s = 0.f;
#pragma unroll
                for (int wv2 = 0; wv2 < 4; ++wv2)
                    s += *(const float*)(smem + ORED_OFF + ((wv2 * 64 + row) * 32 + d0 + i) * 4);
                o[i] = s * inv;
            }
            float* dst = out + (size_t)(win * 49 + row) * 256 + h * 32 + d0;
            float4 o0 = {o[0], o[1], o[2], o[3]};
            float4 o1 = {o[4], o[5], o[6], o[7]};
            *(float4*)dst       = o0;
            *(float4*)(dst + 4) = o1;
        }
    }
}

// ---------------- launch ----------------
extern "C" void kernel_launch(void* const* d_in, const int* in_sizes, int n_in,
                              void* d_out, int out_size, void* d_ws, size_t ws_size,
                              hipStream_t stream)
{
    const float* x      = (const float*)d_in[0];
    const float* pool0  = (const float*)d_in[1];
    const float* clip1  = (const float*)d_in[2];
    const float* clip2  = (const float*)d_in[3];
    const float* clip3  = (const float*)d_in[4];
    const float* qkv_w  = (const float*)d_in[5];
    const float* qkv_b  = (const float*)d_in[6];
    const float* proj_w = (const float*)d_in[7];
    const float* proj_b = (const float*)d_in[8];
    float* out = (float*)d_out;

    float* ws   = (float*)d_ws;
    float* qkv  = ws;                          // 25088*768
    float* kv1  = qkv + 25088ull * 768;        // 25088*512
    float* kv2  = kv1 + 25088ull * 512;        // 12800*512
    float* kv3  = kv2 + 12800ull * 512;        //  4608*512
    float* attn = kv3 + 4608ull * 512;         // 25088*256
    __hip_bfloat16* wq = (__hip_bfloat16*)(attn + 25088ull * 256);  // [768][256]
    __hip_bfloat16* wp = wq + 768ull * 256;                         // [256][256]

    wprep_kernel<<<dim3(1024), dim3(256), 0, stream>>>(qkv_w, proj_w, wq, wp);

    // x -> qkv (q|k|v): M=25088, N=768
    gemm_mfma_kernel<<<dim3(6, 196), dim3(256), 0, stream>>>(
        x, wq, qkv_b, qkv, 768);
    // clips -> k|v only (Wt rows 256..767): N=512
    gemm_mfma_kernel<<<dim3(4, 196), dim3(256), 0, stream>>>(
        clip1, wq + 256 * 256, qkv_b + 256, kv1, 512);
    gemm_mfma_kernel<<<dim3(4, 100), dim3(256), 0, stream>>>(
        clip2, wq + 256 * 256, qkv_b + 256, kv2, 512);
    gemm_mfma_kernel<<<dim3(4, 36), dim3(256), 0, stream>>>(
        clip3, wq + 256 * 256, qkv_b + 256, kv3, 512);
    // attention
    attn_kernel<<<dim3(512 * 8), dim3(256), 0, stream>>>(
        qkv, pool0, kv1, kv2, kv3, attn);
    // projection: N=256
    gemm_mfma_kernel<<<dim3(2, 196), dim3(256), 0, stream>>>(
        attn, wp, proj_b, out, 256);
}

// Round 8
// 302.686 us; speedup vs baseline: 3.3887x; 1.2678x over previous
//
#include <hip/hip_runtime.h>
#include <hip/hip_bf16.h>

// CffmTransformerBlock3d3 — round 8 (= r7, resubmitted after broker timeouts).
//  * cvt    : all fp32 activations (x, clip1-3, pool0) -> bf16 once.
//  * GEMM   : m97 structure — global_load_lds(16B) + double-buffered LDS,
//             one barrier per K-tile, bf16 in / bf16-or-fp32 out.
//             clip1+clip2+clip3 fused into one M=42496 launch (contiguous ws).
//  * attn   : bf16 gather (pure 16B copies), K in 4 split planes
//             (conflict-free), Q per-wave from global, bf16 output,
//             ORED stride-33 pad (kills 16-way epilogue conflict).

#define NKEYS 377

typedef unsigned int u32;
typedef unsigned short u16;
typedef __attribute__((ext_vector_type(8))) short bf16x8;
typedef __attribute__((ext_vector_type(8))) unsigned short u16x8;
typedef __attribute__((ext_vector_type(4))) unsigned int u32x4;
typedef __attribute__((ext_vector_type(4))) float f32x4;

__device__ __forceinline__ u16 f2bf(float f) {
    u32 b = __float_as_uint(f);
    b += 0x7FFFu + ((b >> 16) & 1u);
    return (u16)(b >> 16);
}
__device__ __forceinline__ u32 pack2(float lo, float hi) {
    return (u32)f2bf(lo) | ((u32)f2bf(hi) << 16);
}
__device__ __forceinline__ bf16x8 cvt8(float4 x, float4 y) {
    union { bf16x8 v; __hip_bfloat162 h[4]; } un;
    un.h[0] = __float22bfloat162_rn(make_float2(x.x, x.y));
    un.h[1] = __float22bfloat162_rn(make_float2(x.z, x.w));
    un.h[2] = __float22bfloat162_rn(make_float2(y.x, y.y));
    un.h[3] = __float22bfloat162_rn(make_float2(y.z, y.w));
    return un.v;
}

// ---------------- fp32 -> bf16 conversion (grid-stride, 8 elems/thread) ----
__global__ __launch_bounds__(256)
void cvt_kernel(const float* __restrict__ x,  const float* __restrict__ c1,
                const float* __restrict__ c2, const float* __restrict__ c3,
                const float* __restrict__ p0,
                __hip_bfloat16* __restrict__ xb, __hip_bfloat16* __restrict__ c1b,
                __hip_bfloat16* __restrict__ c2b, __hip_bfloat16* __restrict__ c3b,
                __hip_bfloat16* __restrict__ p0b)
{
    const int U0 = 802816, U1 = 1605632, U2 = 2015232, U3 = 2162688, U4 = 2965504;
    for (int u = blockIdx.x * 256 + threadIdx.x; u < U4; u += gridDim.x * 256) {
        const float* s; __hip_bfloat16* d; int o;
        if (u < U0)      { s = x;  d = xb;  o = u; }
        else if (u < U1) { s = c1; d = c1b; o = u - U0; }
        else if (u < U2) { s = c2; d = c2b; o = u - U1; }
        else if (u < U3) { s = c3; d = c3b; o = u - U2; }
        else             { s = p0; d = p0b; o = u - U3; }
        const float4 a = *(const float4*)(s + (size_t)o * 8);
        const float4 b = *(const float4*)(s + (size_t)o * 8 + 4);
        *(bf16x8*)((short*)d + (size_t)o * 8) = cvt8(a, b);
    }
}

// ---------------- weight prep: Wt[n][k] = bf16(W[k][n]) ----------------
__global__ __launch_bounds__(256)
void wprep_kernel(const float* __restrict__ qkv_w,   // [256][768]
                  const float* __restrict__ proj_w,  // [256][256]
                  __hip_bfloat16* __restrict__ wq,   // [768][256]
                  __hip_bfloat16* __restrict__ wp)   // [256][256]
{
    const int n = blockIdx.x;
    const int k = threadIdx.x;
    if (n < 768) wq[n * 256 + k] = __float2bfloat16(qkv_w[k * 768 + n]);
    else         wp[(n - 768) * 256 + k] = __float2bfloat16(proj_w[k * 256 + (n - 768)]);
}

// ---------------- bf16 MFMA GEMM (m97-style) ----------------
// A[M][256] bf16, Bt[N][256] bf16 (K-contig), C + bias (bf16 or fp32 out).
// 128x128 tile, 4 waves, K-tiles of 32, global_load_lds + double buffer,
// ONE barrier per K-tile (loads for t+1 in flight across compute of t).
#define GLD(gsrc, loff)                                                        \
    __builtin_amdgcn_global_load_lds(                                          \
        (const __attribute__((address_space(1))) void*)(gsrc),                 \
        (__attribute__((address_space(3))) void*)(smem + (loff)), 16, 0, 0)

__global__ __launch_bounds__(256)
void gemm_mfma_kernel(const __hip_bfloat16* __restrict__ A,
                      const __hip_bfloat16* __restrict__ Bt,
                      const float* __restrict__ bias,
                      void* __restrict__ Cv, int ldc, int obf)
{
    __shared__ __align__(16) char smem[32768];   // [2] x (A 8KB | B 8KB)

    const int tid = threadIdx.x;
    const int n0 = blockIdx.x * 128, m0 = blockIdx.y * 128;
    const int lane = tid & 63, wv = tid >> 6;
    const int wm = (wv >> 1) << 6, wn = (wv & 1) << 6;
    const int l15 = lane & 15, g = lane >> 4;

    // staging map: LDS linear o = wv*2048 + i*1024 + lane*16 (HW adds lane*16)
    //              row = wv*32 + i*16 + lane/4, colElem = (lane&3)*8
    const int srow = wv * 32 + (lane >> 2);
    const int scol = (lane & 3) << 3;
    const short* Ag = (const short*)A + (size_t)(m0 + srow) * 256 + scol;
    const short* Bg = (const short*)Bt + (size_t)(n0 + srow) * 256 + scol;

    f32x4 acc[4][4];
    const f32x4 z4 = {0.f, 0.f, 0.f, 0.f};
#pragma unroll
    for (int i = 0; i < 4; ++i)
#pragma unroll
        for (int j = 0; j < 4; ++j) acc[i][j] = z4;

    auto stage = [&](int buf, int k0) {
        const int b0 = buf * 16384 + wv * 2048;
        GLD(Ag + k0,            b0);
        GLD(Ag + k0 + 16 * 256, b0 + 1024);
        GLD(Bg + k0,            b0 + 8192);
        GLD(Bg + k0 + 16 * 256, b0 + 8192 + 1024);
    };

    stage(0, 0);
    __syncthreads();                       // tile 0 landed (implicit vmcnt(0))
    int cur = 0;
    for (int kt = 0; kt < 8; ++kt) {
        if (kt < 7) stage(cur ^ 1, (kt + 1) * 32);   // next tile in flight
        const char* Ab = smem + cur * 16384;
        const char* Bb = Ab + 8192;
        bf16x8 af[4], bfr[4];
#pragma unroll
        for (int rb = 0; rb < 4; ++rb)
            af[rb] = *(const bf16x8*)(Ab + (wm + rb * 16 + l15) * 64 + g * 16);
#pragma unroll
        for (int cb = 0; cb < 4; ++cb)
            bfr[cb] = *(const bf16x8*)(Bb + (wn + cb * 16 + l15) * 64 + g * 16);
#pragma unroll
        for (int rb = 0; rb < 4; ++rb)
#pragma unroll
            for (int cb = 0; cb < 4; ++cb)
                acc[rb][cb] = __builtin_amdgcn_mfma_f32_16x16x32_bf16(
                    af[rb], bfr[cb], acc[rb][cb], 0, 0, 0);
        __syncthreads();                   // drains stage; frees buf cur
        cur ^= 1;
    }

    float bcol[4];
#pragma unroll
    for (int cb = 0; cb < 4; ++cb) bcol[cb] = bias[n0 + wn + cb * 16 + l15];
    if (obf) {
        __hip_bfloat16* C = (__hip_bfloat16*)Cv;
#pragma unroll
        for (int rb = 0; rb < 4; ++rb)
#pragma unroll
            for (int r = 0; r < 4; ++r) {
                const int m = m0 + wm + rb * 16 + (g << 2) + r;
                __hip_bfloat16* crow = C + (size_t)m * ldc + n0 + wn + l15;
#pragma unroll
                for (int cb = 0; cb < 4; ++cb)
                    crow[cb * 16] = __float2bfloat16(acc[rb][cb][r] + bcol[cb]);
            }
    } else {
        float* C = (float*)Cv;
#pragma unroll
        for (int rb = 0; rb < 4; ++rb)
#pragma unroll
            for (int r = 0; r < 4; ++r) {
                const int m = m0 + wm + rb * 16 + (g << 2) + r;
                float* crow = C + (size_t)m * ldc + n0 + wn + l15;
#pragma unroll
                for (int cb = 0; cb < 4; ++cb)
                    crow[cb * 16] = acc[rb][cb][r] + bcol[cb];
            }
    }
}

// ---------------- MFMA attention (bf16 in / bf16 out) ----------------
// LDS (bytes):
//  [0,24576)      Vt   32 dim-rows x 768B (keys x 2B, phi-ordered, XOR swz)
//  [24576,49152)  K    4 planes [jq][384][16B]  (conflict-free split)
//  [49152,50176)  SMAX [4][64] f32
//  [50176,51200)  SSUM [4][64] f32
//  [51200,51456)  GMAX [64] f32
//  reuse: PBUF 4x64x80B at 24576 (after QK^T);
//         ORED [4][64][33]f32 at 0 (after PV; 33792B, pad kills 16-way reads)
#define VT_OFF   0
#define KL_OFF   24576
#define SMAX_OFF 49152
#define SSUM_OFF 50176
#define GMAX_OFF 51200
#define PBUF_OFF 24576
#define ORED_OFF 0
#define LDS_SZ   51456

__global__ __launch_bounds__(256)
void attn_kernel(const __hip_bfloat16* __restrict__ qkvb,   // [25088][768]
                 const __hip_bfloat16* __restrict__ pool0b, // [512*12544]
                 const __hip_bfloat16* __restrict__ kv1b,   // [25088][512]
                 const __hip_bfloat16* __restrict__ kv2b,   // [12800][512]
                 const __hip_bfloat16* __restrict__ kv3b,   // [4608][512]
                 __hip_bfloat16* __restrict__ outb)         // [25088][256]
{
    __shared__ __align__(16) char smem[LDS_SZ];

    const int wh  = blockIdx.x;
    const int win = wh >> 3, h = wh & 7;
    const int bb  = win >> 8, wi = (win >> 4) & 15, wj = win & 15;
    const int tid = threadIdx.x;
    const int lane = tid & 63, ww = tid >> 6;
    const int l15 = lane & 15, g = lane >> 4;
    const short* qkv = (const short*)qkvb;

    // ---- Q fragments straight from global (issued before gather) ----
    bf16x8 aq[4];
    const bf16x8 zb = {0, 0, 0, 0, 0, 0, 0, 0};
#pragma unroll
    for (int rb = 0; rb < 4; ++rb) {
        const int r16 = rb * 16 + l15;
        if (r16 < 49) {
            const int aa = r16 / 7, cc = r16 % 7;
            const int row = (bb * 112 + wi * 7 + aa) * 112 + wj * 7 + cc;
            aq[rb] = *(const bf16x8*)(qkv + (size_t)row * 768 + h * 32 + g * 8);
        } else aq[rb] = zb;
    }

    // ---------------- gather K/V (bf16 -> LDS, no conversion) ----------------
    if (tid < 192) {
        const int j0   = tid * 2;
        const int gw   = j0 / 96, rem = j0 % 96;
        const int gk   = rem / 32, gl = (rem % 32) >> 1;
        const int keyA = (gw * 6 + gk * 2) * 16 + gl;
        u16x8 vb[2][4];
#pragma unroll
        for (int s = 0; s < 2; ++s) {
            const int key = keyA + s * 16;
            if (key < NKEYS) {
                const short *kp, *vp;
                if (key < 245) {
                    int aa, cc, hh, ww2;
                    if (key < 49) {
                        aa = key / 7; cc = key % 7;
                        hh = wi * 7 + aa; ww2 = wj * 7 + cc;
                    } else {
                        const int u = key - 49, si = u / 49, rr = u % 49;
                        aa = rr / 7; cc = rr % 7;
                        const int sh = (si < 2) ? -3 : 3;
                        const int sw = (si & 1) ? 3 : -3;
                        hh  = (wi * 7 + aa - sh + 112) % 112;
                        ww2 = (wj * 7 + cc - sw + 112) % 112;
                    }
                    const int row = (bb * 112 + hh) * 112 + ww2;
                    kp = qkv + (size_t)row * 768 + 256 + h * 32;
                    vp = qkv + (size_t)row * 768 + 512 + h * 32;
                } else if (key < 294) {
                    const short* p = (const short*)pool0b + (size_t)win * 12544 + h * 1568 + (key - 245) * 32;
                    kp = p; vp = p;
                } else if (key < 343) {
                    const short* p = (const short*)kv1b + (size_t)(win * 49 + key - 294) * 512 + h * 32;
                    kp = p; vp = p + 256;
                } else if (key < 368) {
                    const short* p = (const short*)kv2b + (size_t)(win * 25 + key - 343) * 512 + h * 32;
                    kp = p; vp = p + 256;
                } else {
                    const short* p = (const short*)kv3b + (size_t)(win * 9 + key - 368) * 512 + h * 32;
                    kp = p; vp = p + 256;
                }
                const u16x8* kp4 = (const u16x8*)kp;
                const u16x8* vp4 = (const u16x8*)vp;
#pragma unroll
                for (int jq = 0; jq < 4; ++jq)
                    *(u16x8*)(smem + KL_OFF + jq * 6144 + key * 16) = kp4[jq];
#pragma unroll
                for (int jq = 0; jq < 4; ++jq) vb[s][jq] = vp4[jq];
            } else {
                const u16x8 z = {0, 0, 0, 0, 0, 0, 0, 0};
#pragma unroll
                for (int jq = 0; jq < 4; ++jq)
                    *(u16x8*)(smem + KL_OFF + jq * 6144 + key * 16) = z;
#pragma unroll
                for (int jq = 0; jq < 4; ++jq) vb[s][jq] = z;
            }
        }
        // Vt transpose: dim-major rows, u32 col pair (keyA, keyA+16)
#pragma unroll
        for (int d = 0; d < 32; ++d) {
            int byte = d * 768 + tid * 4;
            byte ^= (d & 7) << 4;
            const u32 lo = vb[0][d >> 3][d & 7];
            const u32 hi = vb[1][d >> 3][d & 7];
            *(u32*)(smem + VT_OFF + byte) = lo | (hi << 16);
        }
    }
    __syncthreads();   // B0: gather complete

    // ---------------- QK^T (raw scores; scale folded into exp) ----------------
    f32x4 S[4][6];
    const f32x4 z4 = {0.f, 0.f, 0.f, 0.f};
#pragma unroll
    for (int c = 0; c < 6; ++c) {
        const int key = (ww * 6 + c) * 16 + l15;
        // plane g supplies dims [g*8, g*8+8) of `key` — exactly the B-fragment
        const bf16x8 bk = *(const bf16x8*)(smem + KL_OFF + g * 6144 + key * 16);
#pragma unroll
        for (int rb = 0; rb < 4; ++rb)
            S[rb][c] = __builtin_amdgcn_mfma_f32_16x16x32_bf16(aq[rb], bk, z4, 0, 0, 0);
    }

    // ---------------- row max ----------------
    float mx[4][4];
#pragma unroll
    for (int rb = 0; rb < 4; ++rb)
#pragma unroll
        for (int r = 0; r < 4; ++r) {
            float v = S[rb][0][r];
#pragma unroll
            for (int c = 1; c < 6; ++c) v = fmaxf(v, S[rb][c][r]);
            mx[rb][r] = v;
        }
#pragma unroll
    for (int mvar = 1; mvar <= 8; mvar <<= 1)
#pragma unroll
        for (int rb = 0; rb < 4; ++rb)
#pragma unroll
            for (int r = 0; r < 4; ++r)
                mx[rb][r] = fmaxf(mx[rb][r], __shfl_xor(mx[rb][r], mvar, 64));
    {
        const int drb = l15 >> 2, dr = l15 & 3;
        const int row = 16 * drb + 4 * g + dr;
        *(float*)(smem + SMAX_OFF + (ww * 64 + row) * 4) = mx[drb][dr];
    }
    __syncthreads();   // B1: strip maxima ready; K reads done

    if (tid < 64) {
        float gmv = *(const float*)(smem + SMAX_OFF + tid * 4);
#pragma unroll
        for (int wv2 = 1; wv2 < 4; ++wv2)
            gmv = fmaxf(gmv, *(const float*)(smem + SMAX_OFF + (wv2 * 64 + tid) * 4));
        *(float*)(smem + GMAX_OFF + tid * 4) = gmv;
    }
    __syncthreads();   // B2: gmax ready

    float gm[4][4];
#pragma unroll
    for (int rb = 0; rb < 4; ++rb)
#pragma unroll
        for (int r = 0; r < 4; ++r)
            gm[rb][r] = *(const float*)(smem + GMAX_OFF + (16 * rb + 4 * g + r) * 4);

    const float scale = 0.17677669529663687f;   // 32^-0.5
    float sm[4][4];
#pragma unroll
    for (int rb = 0; rb < 4; ++rb)
#pragma unroll
        for (int r = 0; r < 4; ++r) sm[rb][r] = 0.f;

#pragma unroll
    for (int c = 0; c < 6; ++c) {
        const bool tail = (ww == 3) && (c == 5) && (l15 >= 9);   // keys >= 377
#pragma unroll
        for (int rb = 0; rb < 4; ++rb) {
            f32x4 p;
#pragma unroll
            for (int r = 0; r < 4; ++r) {
                const float e = tail ? 0.f : __expf((S[rb][c][r] - gm[rb][r]) * scale);
                p[r] = e;
                sm[rb][r] += e;
            }
            S[rb][c] = p;
        }
    }
#pragma unroll
    for (int mvar = 1; mvar <= 8; mvar <<= 1)
#pragma unroll
        for (int rb = 0; rb < 4; ++rb)
#pragma unroll
            for (int r = 0; r < 4; ++r)
                sm[rb][r] += __shfl_xor(sm[rb][r], mvar, 64);
    {
        const int drb = l15 >> 2, dr = l15 & 3;
        const int row = 16 * drb + 4 * g + dr;
        *(float*)(smem + SSUM_OFF + (ww * 64 + row) * 4) = sm[drb][dr];
    }

    // ---------------- PV ----------------
    f32x4 O_[4][2];
#pragma unroll
    for (int rb = 0; rb < 4; ++rb) { O_[rb][0] = z4; O_[rb][1] = z4; }

    char* pbuf = smem + PBUF_OFF + ww * 5120;   // [64][80B], K region (dead)
#pragma unroll
    for (int kcl = 0; kcl < 3; ++kcl) {
#pragma unroll
        for (int rb = 0; rb < 4; ++rb)
#pragma unroll
            for (int r = 0; r < 4; ++r) {
                const int row = 16 * rb + 4 * g + r;
                *(u32*)(pbuf + row * 80 + l15 * 4) =
                    pack2(S[rb][2 * kcl][r], S[rb][2 * kcl + 1][r]);
            }
        bf16x8 bv[2];
#pragma unroll
        for (int nc = 0; nc < 2; ++nc) {
            const int dim = 16 * nc + l15;
            int byte = dim * 768 + ww * 192 + kcl * 64 + g * 16;
            byte ^= (dim & 7) << 4;
            bv[nc] = *(const bf16x8*)(smem + VT_OFF + byte);
        }
#pragma unroll
        for (int rb = 0; rb < 4; ++rb) {
            const bf16x8 ap = *(const bf16x8*)(pbuf + (16 * rb + l15) * 80 + g * 16);
            O_[rb][0] = __builtin_amdgcn_mfma_f32_16x16x32_bf16(ap, bv[0], O_[rb][0], 0, 0, 0);
            O_[rb][1] = __builtin_amdgcn_mfma_f32_16x16x32_bf16(ap, bv[1], O_[rb][1], 0, 0, 0);
        }
    }
    __syncthreads();   // B3: Vt / pbuf dead

    // ---------------- cross-wave O reduction (stride 33: pad) ----------------
#pragma unroll
    for (int rb = 0; rb < 4; ++rb)
#pragma unroll
        for (int nc = 0; nc < 2; ++nc)
#pragma unroll
            for (int r = 0; r < 4; ++r) {
                const int row = 16 * rb + 4 * g + r;
                const int col = 16 * nc + l15;
                *(float*)(smem + ORED_OFF + ((ww * 64 + row) * 33 + col) * 4) = O_[rb][nc][r];
            }
    __syncthreads();   // B4

    {
        const int row = tid >> 2, d0 = (tid & 3) * 8;
        if (row < 49) {
            float lt = 0.f;
#pragma unroll
            for (int wv2 = 0; wv2 < 4; ++wv2)
                lt += *(const float*)(smem + SSUM_OFF + (wv2 * 64 + row) * 4);
            const float inv = 1.0f / lt;
            float o[8];
#pragma unroll
            for (int i = 0; i < 8; ++i) {
                float s = 0.f;
#pragma unroll
                for (int wv2 = 0; wv2 < 4; ++wv2)
                    s += *(const float*)(smem + ORED_OFF + ((wv2 * 64 + row) * 33 + d0 + i) * 4);
                o[i] = s * inv;
            }
            u32x4 pk;
#pragma unroll
            for (int i = 0; i < 4; ++i) pk[i] = pack2(o[2 * i], o[2 * i + 1]);
            *(u32x4*)((short*)outb + (size_t)(win * 49 + row) * 256 + h * 32 + d0) = pk;
        }
    }
}

// ---------------- launch ----------------
extern "C" void kernel_launch(void* const* d_in, const int* in_sizes, int n_in,
                              void* d_out, int out_size, void* d_ws, size_t ws_size,
                              hipStream_t stream)
{
    const float* x      = (const float*)d_in[0];
    const float* pool0  = (const float*)d_in[1];
    const float* clip1  = (const float*)d_in[2];
    const float* clip2  = (const float*)d_in[3];
    const float* clip3  = (const float*)d_in[4];
    const float* qkv_w  = (const float*)d_in[5];
    const float* qkv_b  = (const float*)d_in[6];
    const float* proj_w = (const float*)d_in[7];
    const float* proj_b = (const float*)d_in[8];
    float* out = (float*)d_out;

    // workspace (all bf16 = shorts); clip inputs c1b|c2b|c3b contiguous,
    // outputs kv1b|kv2b|kv3b contiguous -> one fused clip GEMM.
    __hip_bfloat16* ws  = (__hip_bfloat16*)d_ws;
    __hip_bfloat16* qkvb = ws;                          // 25088*768
    __hip_bfloat16* kv1b = qkvb + 25088ull * 768;       // 25088*512
    __hip_bfloat16* kv2b = kv1b + 25088ull * 512;       // 12800*512
    __hip_bfloat16* kv3b = kv2b + 12800ull * 512;       //  4608*512
    __hip_bfloat16* attnb = kv3b + 4608ull * 512;       // 25088*256
    __hip_bfloat16* xb   = attnb + 25088ull * 256;      // 25088*256
    __hip_bfloat16* c1b  = xb + 25088ull * 256;         // 25088*256
    __hip_bfloat16* c2b  = c1b + 25088ull * 256;        // 12800*256
    __hip_bfloat16* c3b  = c2b + 12800ull * 256;        //  4608*256
    __hip_bfloat16* p0b  = c3b + 4608ull * 256;         // 512*12544
    __hip_bfloat16* wq   = p0b + 512ull * 12544;        // 768*256
    __hip_bfloat16* wp   = wq + 768ull * 256;           // 256*256

    cvt_kernel<<<dim3(2048), dim3(256), 0, stream>>>(
        x, clip1, clip2, clip3, pool0, xb, c1b, c2b, c3b, p0b);
    wprep_kernel<<<dim3(1024), dim3(256), 0, stream>>>(qkv_w, proj_w, wq, wp);

    // x -> qkv (bf16 out): M=25088 (196 tiles), N=768
    gemm_mfma_kernel<<<dim3(6, 196), dim3(256), 0, stream>>>(
        xb, wq, qkv_b, qkvb, 768, 1);
    // clips -> k|v (bf16 out): fused M = 25088+12800+4608 = 42496 (332 tiles)
    gemm_mfma_kernel<<<dim3(4, 332), dim3(256), 0, stream>>>(
        c1b, wq + 256 * 256, qkv_b + 256, kv1b, 512, 1);
    // attention (bf16 in/out)
    attn_kernel<<<dim3(512 * 8), dim3(256), 0, stream>>>(
        qkvb, p0b, kv1b, kv2b, kv3b, attnb);
    // projection (fp32 out): N=256
    gemm_mfma_kernel<<<dim3(2, 196), dim3(256), 0, stream>>>(
        attnb, wp, proj_b, out, 256, 0);
}

// Round 9
// 294.043 us; speedup vs baseline: 3.4883x; 1.0294x over previous
//
#include <hip/hip_runtime.h>
#include <hip/hip_bf16.h>

// CffmTransformerBlock3d3 — round 9 (= r8 + bijective XCD-aware swizzles).
//  * attn  : blocks chunked per-XCD (64 windows x 8 heads per XCD) so rolled
//            K/V reuse and head-adjacency hit the per-XCD L2.
//  * GEMM  : 1D grid + XCD chunking (A-tile panel + whole B panel L2-resident).
//  All math bitwise-identical to r8.

#define NKEYS 377

typedef unsigned int u32;
typedef unsigned short u16;
typedef __attribute__((ext_vector_type(8))) short bf16x8;
typedef __attribute__((ext_vector_type(8))) unsigned short u16x8;
typedef __attribute__((ext_vector_type(4))) unsigned int u32x4;
typedef __attribute__((ext_vector_type(4))) float f32x4;

__device__ __forceinline__ u16 f2bf(float f) {
    u32 b = __float_as_uint(f);
    b += 0x7FFFu + ((b >> 16) & 1u);
    return (u16)(b >> 16);
}
__device__ __forceinline__ u32 pack2(float lo, float hi) {
    return (u32)f2bf(lo) | ((u32)f2bf(hi) << 16);
}
__device__ __forceinline__ bf16x8 cvt8(float4 x, float4 y) {
    union { bf16x8 v; __hip_bfloat162 h[4]; } un;
    un.h[0] = __float22bfloat162_rn(make_float2(x.x, x.y));
    un.h[1] = __float22bfloat162_rn(make_float2(x.z, x.w));
    un.h[2] = __float22bfloat162_rn(make_float2(y.x, y.y));
    un.h[3] = __float22bfloat162_rn(make_float2(y.z, y.w));
    return un.v;
}

// ---------------- fp32 -> bf16 conversion (grid-stride, 8 elems/thread) ----
__global__ __launch_bounds__(256)
void cvt_kernel(const float* __restrict__ x,  const float* __restrict__ c1,
                const float* __restrict__ c2, const float* __restrict__ c3,
                const float* __restrict__ p0,
                __hip_bfloat16* __restrict__ xb, __hip_bfloat16* __restrict__ c1b,
                __hip_bfloat16* __restrict__ c2b, __hip_bfloat16* __restrict__ c3b,
                __hip_bfloat16* __restrict__ p0b)
{
    const int U0 = 802816, U1 = 1605632, U2 = 2015232, U3 = 2162688, U4 = 2965504;
    for (int u = blockIdx.x * 256 + threadIdx.x; u < U4; u += gridDim.x * 256) {
        const float* s; __hip_bfloat16* d; int o;
        if (u < U0)      { s = x;  d = xb;  o = u; }
        else if (u < U1) { s = c1; d = c1b; o = u - U0; }
        else if (u < U2) { s = c2; d = c2b; o = u - U1; }
        else if (u < U3) { s = c3; d = c3b; o = u - U2; }
        else             { s = p0; d = p0b; o = u - U3; }
        const float4 a = *(const float4*)(s + (size_t)o * 8);
        const float4 b = *(const float4*)(s + (size_t)o * 8 + 4);
        *(bf16x8*)((short*)d + (size_t)o * 8) = cvt8(a, b);
    }
}

// ---------------- weight prep: Wt[n][k] = bf16(W[k][n]) ----------------
__global__ __launch_bounds__(256)
void wprep_kernel(const float* __restrict__ qkv_w,   // [256][768]
                  const float* __restrict__ proj_w,  // [256][256]
                  __hip_bfloat16* __restrict__ wq,   // [768][256]
                  __hip_bfloat16* __restrict__ wp)   // [256][256]
{
    const int n = blockIdx.x;
    const int k = threadIdx.x;
    if (n < 768) wq[n * 256 + k] = __float2bfloat16(qkv_w[k * 768 + n]);
    else         wp[(n - 768) * 256 + k] = __float2bfloat16(proj_w[k * 256 + (n - 768)]);
}

// ---------------- bf16 MFMA GEMM (m97-style, XCD-swizzled 1D grid) ----------
// A[M][256] bf16, Bt[N][256] bf16 (K-contig), C + bias (bf16 or fp32 out).
// 128x128 tile, 4 waves, K-tiles of 32, global_load_lds + double buffer,
// ONE barrier per K-tile.  Grid: 1D nx*ny blocks (must be divisible by 8).
#define GLD(gsrc, loff)                                                        \
    __builtin_amdgcn_global_load_lds(                                          \
        (const __attribute__((address_space(1))) void*)(gsrc),                 \
        (__attribute__((address_space(3))) void*)(smem + (loff)), 16, 0, 0)

__global__ __launch_bounds__(256)
void gemm_mfma_kernel(const __hip_bfloat16* __restrict__ A,
                      const __hip_bfloat16* __restrict__ Bt,
                      const float* __restrict__ bias,
                      void* __restrict__ Cv, int ldc, int obf, int nx)
{
    __shared__ __align__(16) char smem[32768];   // [2] x (A 8KB | B 8KB)

    // bijective XCD swizzle: gridDim.x divisible by 8
    const int cpx = gridDim.x >> 3;
    const int bid = blockIdx.x;
    const int bs  = (bid & 7) * cpx + (bid >> 3);
    const int n0  = (bs % nx) * 128;
    const int m0  = (bs / nx) * 128;

    const int tid = threadIdx.x;
    const int lane = tid & 63, wv = tid >> 6;
    const int wm = (wv >> 1) << 6, wn = (wv & 1) << 6;
    const int l15 = lane & 15, g = lane >> 4;

    const int srow = wv * 32 + (lane >> 2);
    const int scol = (lane & 3) << 3;
    const short* Ag = (const short*)A + (size_t)(m0 + srow) * 256 + scol;
    const short* Bg = (const short*)Bt + (size_t)(n0 + srow) * 256 + scol;

    f32x4 acc[4][4];
    const f32x4 z4 = {0.f, 0.f, 0.f, 0.f};
#pragma unroll
    for (int i = 0; i < 4; ++i)
#pragma unroll
        for (int j = 0; j < 4; ++j) acc[i][j] = z4;

    auto stage = [&](int buf, int k0) {
        const int b0 = buf * 16384 + wv * 2048;
        GLD(Ag + k0,            b0);
        GLD(Ag + k0 + 16 * 256, b0 + 1024);
        GLD(Bg + k0,            b0 + 8192);
        GLD(Bg + k0 + 16 * 256, b0 + 8192 + 1024);
    };

    stage(0, 0);
    __syncthreads();                       // tile 0 landed (implicit vmcnt(0))
    int cur = 0;
    for (int kt = 0; kt < 8; ++kt) {
        if (kt < 7) stage(cur ^ 1, (kt + 1) * 32);   // next tile in flight
        const char* Ab = smem + cur * 16384;
        const char* Bb = Ab + 8192;
        bf16x8 af[4], bfr[4];
#pragma unroll
        for (int rb = 0; rb < 4; ++rb)
            af[rb] = *(const bf16x8*)(Ab + (wm + rb * 16 + l15) * 64 + g * 16);
#pragma unroll
        for (int cb = 0; cb < 4; ++cb)
            bfr[cb] = *(const bf16x8*)(Bb + (wn + cb * 16 + l15) * 64 + g * 16);
#pragma unroll
        for (int rb = 0; rb < 4; ++rb)
#pragma unroll
            for (int cb = 0; cb < 4; ++cb)
                acc[rb][cb] = __builtin_amdgcn_mfma_f32_16x16x32_bf16(
                    af[rb], bfr[cb], acc[rb][cb], 0, 0, 0);
        __syncthreads();                   // drains stage; frees buf cur
        cur ^= 1;
    }

    float bcol[4];
#pragma unroll
    for (int cb = 0; cb < 4; ++cb) bcol[cb] = bias[n0 + wn + cb * 16 + l15];
    if (obf) {
        __hip_bfloat16* C = (__hip_bfloat16*)Cv;
#pragma unroll
        for (int rb = 0; rb < 4; ++rb)
#pragma unroll
            for (int r = 0; r < 4; ++r) {
                const int m = m0 + wm + rb * 16 + (g << 2) + r;
                __hip_bfloat16* crow = C + (size_t)m * ldc + n0 + wn + l15;
#pragma unroll
                for (int cb = 0; cb < 4; ++cb)
                    crow[cb * 16] = __float2bfloat16(acc[rb][cb][r] + bcol[cb]);
            }
    } else {
        float* C = (float*)Cv;
#pragma unroll
        for (int rb = 0; rb < 4; ++rb)
#pragma unroll
            for (int r = 0; r < 4; ++r) {
                const int m = m0 + wm + rb * 16 + (g << 2) + r;
                float* crow = C + (size_t)m * ldc + n0 + wn + l15;
#pragma unroll
                for (int cb = 0; cb < 4; ++cb)
                    crow[cb * 16] = acc[rb][cb][r] + bcol[cb];
            }
    }
}

// ---------------- MFMA attention (bf16 in / bf16 out) ----------------
// LDS layout identical to r8.
#define VT_OFF   0
#define KL_OFF   24576
#define SMAX_OFF 49152
#define SSUM_OFF 50176
#define GMAX_OFF 51200
#define PBUF_OFF 24576
#define ORED_OFF 0
#define LDS_SZ   51456

__global__ __launch_bounds__(256)
void attn_kernel(const __hip_bfloat16* __restrict__ qkvb,   // [25088][768]
                 const __hip_bfloat16* __restrict__ pool0b, // [512*12544]
                 const __hip_bfloat16* __restrict__ kv1b,   // [25088][512]
                 const __hip_bfloat16* __restrict__ kv2b,   // [12800][512]
                 const __hip_bfloat16* __restrict__ kv3b,   // [4608][512]
                 __hip_bfloat16* __restrict__ outb)         // [25088][256]
{
    __shared__ __align__(16) char smem[LDS_SZ];

    // bijective XCD swizzle: 4096 blocks -> 512 consecutive (64 windows x 8
    // heads) per XCD so rolled-window K/V reuse hits the per-XCD L2.
    const int bid = blockIdx.x;
    const int wh  = (bid & 7) * 512 + (bid >> 3);
    const int win = wh >> 3, h = wh & 7;
    const int bb  = win >> 8, wi = (win >> 4) & 15, wj = win & 15;
    const int tid = threadIdx.x;
    const int lane = tid & 63, ww = tid >> 6;
    const int l15 = lane & 15, g = lane >> 4;
    const short* qkv = (const short*)qkvb;

    // ---- Q fragments straight from global (issued before gather) ----
    bf16x8 aq[4];
    const bf16x8 zb = {0, 0, 0, 0, 0, 0, 0, 0};
#pragma unroll
    for (int rb = 0; rb < 4; ++rb) {
        const int r16 = rb * 16 + l15;
        if (r16 < 49) {
            const int aa = r16 / 7, cc = r16 % 7;
            const int row = (bb * 112 + wi * 7 + aa) * 112 + wj * 7 + cc;
            aq[rb] = *(const bf16x8*)(qkv + (size_t)row * 768 + h * 32 + g * 8);
        } else aq[rb] = zb;
    }

    // ---------------- gather K/V (bf16 -> LDS, no conversion) ----------------
    if (tid < 192) {
        const int j0   = tid * 2;
        const int gw   = j0 / 96, rem = j0 % 96;
        const int gk   = rem / 32, gl = (rem % 32) >> 1;
        const int keyA = (gw * 6 + gk * 2) * 16 + gl;
        u16x8 vb[2][4];
#pragma unroll
        for (int s = 0; s < 2; ++s) {
            const int key = keyA + s * 16;
            if (key < NKEYS) {
                const short *kp, *vp;
                if (key < 245) {
                    int aa, cc, hh, ww2;
                    if (key < 49) {
                        aa = key / 7; cc = key % 7;
                        hh = wi * 7 + aa; ww2 = wj * 7 + cc;
                    } else {
                        const int u = key - 49, si = u / 49, rr = u % 49;
                        aa = rr / 7; cc = rr % 7;
                        const int sh = (si < 2) ? -3 : 3;
                        const int sw = (si & 1) ? 3 : -3;
                        hh  = (wi * 7 + aa - sh + 112) % 112;
                        ww2 = (wj * 7 + cc - sw + 112) % 112;
                    }
                    const int row = (bb * 112 + hh) * 112 + ww2;
                    kp = qkv + (size_t)row * 768 + 256 + h * 32;
                    vp = qkv + (size_t)row * 768 + 512 + h * 32;
                } else if (key < 294) {
                    const short* p = (const short*)pool0b + (size_t)win * 12544 + h * 1568 + (key - 245) * 32;
                    kp = p; vp = p;
                } else if (key < 343) {
                    const short* p = (const short*)kv1b + (size_t)(win * 49 + key - 294) * 512 + h * 32;
                    kp = p; vp = p + 256;
                } else if (key < 368) {
                    const short* p = (const short*)kv2b + (size_t)(win * 25 + key - 343) * 512 + h * 32;
                    kp = p; vp = p + 256;
                } else {
                    const short* p = (const short*)kv3b + (size_t)(win * 9 + key - 368) * 512 + h * 32;
                    kp = p; vp = p + 256;
                }
                const u16x8* kp4 = (const u16x8*)kp;
                const u16x8* vp4 = (const u16x8*)vp;
#pragma unroll
                for (int jq = 0; jq < 4; ++jq)
                    *(u16x8*)(smem + KL_OFF + jq * 6144 + key * 16) = kp4[jq];
#pragma unroll
                for (int jq = 0; jq < 4; ++jq) vb[s][jq] = vp4[jq];
            } else {
                const u16x8 z = {0, 0, 0, 0, 0, 0, 0, 0};
#pragma unroll
                for (int jq = 0; jq < 4; ++jq)
                    *(u16x8*)(smem + KL_OFF + jq * 6144 + key * 16) = z;
#pragma unroll
                for (int jq = 0; jq < 4; ++jq) vb[s][jq] = z;
            }
        }
        // Vt transpose: dim-major rows, u32 col pair (keyA, keyA+16)
#pragma unroll
        for (int d = 0; d < 32; ++d) {
            int byte = d * 768 + tid * 4;
            byte ^= (d & 7) << 4;
            const u32 lo = vb[0][d >> 3][d & 7];
            const u32 hi = vb[1][d >> 3][d & 7];
            *(u32*)(smem + VT_OFF + byte) = lo | (hi << 16);
        }
    }
    __syncthreads();   // B0: gather complete

    // ---------------- QK^T (raw scores; scale folded into exp) ----------------
    f32x4 S[4][6];
    const f32x4 z4 = {0.f, 0.f, 0.f, 0.f};
#pragma unroll
    for (int c = 0; c < 6; ++c) {
        const int key = (ww * 6 + c) * 16 + l15;
        const bf16x8 bk = *(const bf16x8*)(smem + KL_OFF + g * 6144 + key * 16);
#pragma unroll
        for (int rb = 0; rb < 4; ++rb)
            S[rb][c] = __builtin_amdgcn_mfma_f32_16x16x32_bf16(aq[rb], bk, z4, 0, 0, 0);
    }

    // ---------------- row max ----------------
    float mx[4][4];
#pragma unroll
    for (int rb = 0; rb < 4; ++rb)
#pragma unroll
        for (int r = 0; r < 4; ++r) {
            float v = S[rb][0][r];
#pragma unroll
            for (int c = 1; c < 6; ++c) v = fmaxf(v, S[rb][c][r]);
            mx[rb][r] = v;
        }
#pragma unroll
    for (int mvar = 1; mvar <= 8; mvar <<= 1)
#pragma unroll
        for (int rb = 0; rb < 4; ++rb)
#pragma unroll
            for (int r = 0; r < 4; ++r)
                mx[rb][r] = fmaxf(mx[rb][r], __shfl_xor(mx[rb][r], mvar, 64));
    {
        const int drb = l15 >> 2, dr = l15 & 3;
        const int row = 16 * drb + 4 * g + dr;
        *(float*)(smem + SMAX_OFF + (ww * 64 + row) * 4) = mx[drb][dr];
    }
    __syncthreads();   // B1: strip maxima ready; K reads done

    if (tid < 64) {
        float gmv = *(const float*)(smem + SMAX_OFF + tid * 4);
#pragma unroll
        for (int wv2 = 1; wv2 < 4; ++wv2)
            gmv = fmaxf(gmv, *(const float*)(smem + SMAX_OFF + (wv2 * 64 + tid) * 4));
        *(float*)(smem + GMAX_OFF + tid * 4) = gmv;
    }
    __syncthreads();   // B2: gmax ready

    float gm[4][4];
#pragma unroll
    for (int rb = 0; rb < 4; ++rb)
#pragma unroll
        for (int r = 0; r < 4; ++r)
            gm[rb][r] = *(const float*)(smem + GMAX_OFF + (16 * rb + 4 * g + r) * 4);

    const float scale = 0.17677669529663687f;   // 32^-0.5
    float sm[4][4];
#pragma unroll
    for (int rb = 0; rb < 4; ++rb)
#pragma unroll
        for (int r = 0; r < 4; ++r) sm[rb][r] = 0.f;

#pragma unroll
    for (int c = 0; c < 6; ++c) {
        const bool tail = (ww == 3) && (c == 5) && (l15 >= 9);   // keys >= 377
#pragma unroll
        for (int rb = 0; rb < 4; ++rb) {
            f32x4 p;
#pragma unroll
            for (int r = 0; r < 4; ++r) {
                const float e = tail ? 0.f : __expf((S[rb][c][r] - gm[rb][r]) * scale);
                p[r] = e;
                sm[rb][r] += e;
            }
            S[rb][c] = p;
        }
    }
#pragma unroll
    for (int mvar = 1; mvar <= 8; mvar <<= 1)
#pragma unroll
        for (int rb = 0; rb < 4; ++rb)
#pragma unroll
            for (int r = 0; r < 4; ++r)
                sm[rb][r] += __shfl_xor(sm[rb][r], mvar, 64);
    {
        const int drb = l15 >> 2, dr = l15 & 3;
        const int row = 16 * drb + 4 * g + dr;
        *(float*)(smem + SSUM_OFF + (ww * 64 + row) * 4) = sm[drb][dr];
    }

    // ---------------- PV ----------------
    f32x4 O_[4][2];
#pragma unroll
    for (int rb = 0; rb < 4; ++rb) { O_[rb][0] = z4; O_[rb][1] = z4; }

    char* pbuf = smem + PBUF_OFF + ww * 5120;   // [64][80B], K region (dead)
#pragma unroll
    for (int kcl = 0; kcl < 3; ++kcl) {
#pragma unroll
        for (int rb = 0; rb < 4; ++rb)
#pragma unroll
            for (int r = 0; r < 4; ++r) {
                const int row = 16 * rb + 4 * g + r;
                *(u32*)(pbuf + row * 80 + l15 * 4) =
                    pack2(S[rb][2 * kcl][r], S[rb][2 * kcl + 1][r]);
            }
        bf16x8 bv[2];
#pragma unroll
        for (int nc = 0; nc < 2; ++nc) {
            const int dim = 16 * nc + l15;
            int byte = dim * 768 + ww * 192 + kcl * 64 + g * 16;
            byte ^= (dim & 7) << 4;
            bv[nc] = *(const bf16x8*)(smem + VT_OFF + byte);
        }
#pragma unroll
        for (int rb = 0; rb < 4; ++rb) {
            const bf16x8 ap = *(const bf16x8*)(pbuf + (16 * rb + l15) * 80 + g * 16);
            O_[rb][0] = __builtin_amdgcn_mfma_f32_16x16x32_bf16(ap, bv[0], O_[rb][0], 0, 0, 0);
            O_[rb][1] = __builtin_amdgcn_mfma_f32_16x16x32_bf16(ap, bv[1], O_[rb][1], 0, 0, 0);
        }
    }
    __syncthreads();   // B3: Vt / pbuf dead

    // ---------------- cross-wave O reduction (stride 33: pad) ----------------
#pragma unroll
    for (int rb = 0; rb < 4; ++rb)
#pragma unroll
        for (int nc = 0; nc < 2; ++nc)
#pragma unroll
            for (int r = 0; r < 4; ++r) {
                const int row = 16 * rb + 4 * g + r;
                const int col = 16 * nc + l15;
                *(float*)(smem + ORED_OFF + ((ww * 64 + row) * 33 + col) * 4) = O_[rb][nc][r];
            }
    __syncthreads();   // B4

    {
        const int row = tid >> 2, d0 = (tid & 3) * 8;
        if (row < 49) {
            float lt = 0.f;
#pragma unroll
            for (int wv2 = 0; wv2 < 4; ++wv2)
                lt += *(const float*)(smem + SSUM_OFF + (wv2 * 64 + row) * 4);
            const float inv = 1.0f / lt;
            float o[8];
#pragma unroll
            for (int i = 0; i < 8; ++i) {
                float s = 0.f;
#pragma unroll
                for (int wv2 = 0; wv2 < 4; ++wv2)
                    s += *(const float*)(smem + ORED_OFF + ((wv2 * 64 + row) * 33 + d0 + i) * 4);
                o[i] = s * inv;
            }
            u32x4 pk;
#pragma unroll
            for (int i = 0; i < 4; ++i) pk[i] = pack2(o[2 * i], o[2 * i + 1]);
            *(u32x4*)((short*)outb + (size_t)(win * 49 + row) * 256 + h * 32 + d0) = pk;
        }
    }
}

// ---------------- launch ----------------
extern "C" void kernel_launch(void* const* d_in, const int* in_sizes, int n_in,
                              void* d_out, int out_size, void* d_ws, size_t ws_size,
                              hipStream_t stream)
{
    const float* x      = (const float*)d_in[0];
    const float* pool0  = (const float*)d_in[1];
    const float* clip1  = (const float*)d_in[2];
    const float* clip2  = (const float*)d_in[3];
    const float* clip3  = (const float*)d_in[4];
    const float* qkv_w  = (const float*)d_in[5];
    const float* qkv_b  = (const float*)d_in[6];
    const float* proj_w = (const float*)d_in[7];
    const float* proj_b = (const float*)d_in[8];
    float* out = (float*)d_out;

    __hip_bfloat16* ws  = (__hip_bfloat16*)d_ws;
    __hip_bfloat16* qkvb = ws;                          // 25088*768
    __hip_bfloat16* kv1b = qkvb + 25088ull * 768;       // 25088*512
    __hip_bfloat16* kv2b = kv1b + 25088ull * 512;       // 12800*512
    __hip_bfloat16* kv3b = kv2b + 12800ull * 512;       //  4608*512
    __hip_bfloat16* attnb = kv3b + 4608ull * 512;       // 25088*256
    __hip_bfloat16* xb   = attnb + 25088ull * 256;      // 25088*256
    __hip_bfloat16* c1b  = xb + 25088ull * 256;         // 25088*256
    __hip_bfloat16* c2b  = c1b + 25088ull * 256;        // 12800*256
    __hip_bfloat16* c3b  = c2b + 12800ull * 256;        //  4608*256
    __hip_bfloat16* p0b  = c3b + 4608ull * 256;         // 512*12544
    __hip_bfloat16* wq   = p0b + 512ull * 12544;        // 768*256
    __hip_bfloat16* wp   = wq + 768ull * 256;           // 256*256

    cvt_kernel<<<dim3(2048), dim3(256), 0, stream>>>(
        x, clip1, clip2, clip3, pool0, xb, c1b, c2b, c3b, p0b);
    wprep_kernel<<<dim3(1024), dim3(256), 0, stream>>>(qkv_w, proj_w, wq, wp);

    // x -> qkv (bf16 out): 6 x 196 = 1176 blocks (%8==0)
    gemm_mfma_kernel<<<dim3(1176), dim3(256), 0, stream>>>(
        xb, wq, qkv_b, qkvb, 768, 1, 6);
    // clips -> k|v (bf16 out): fused M=42496 -> 4 x 332 = 1328 blocks (%8==0)
    gemm_mfma_kernel<<<dim3(1328), dim3(256), 0, stream>>>(
        c1b, wq + 256 * 256, qkv_b + 256, kv1b, 512, 1, 4);
    // attention (bf16 in/out), XCD-chunked
    attn_kernel<<<dim3(512 * 8), dim3(256), 0, stream>>>(
        qkvb, p0b, kv1b, kv2b, kv3b, attnb);
    // projection (fp32 out): 2 x 196 = 392 blocks (%8==0)
    gemm_mfma_kernel<<<dim3(392), dim3(256), 0, stream>>>(
        attnb, wp, proj_b, out, 256, 0, 2);
}